// Round 18
// baseline (108.306 us; speedup 1.0000x reference)
//
#include <hip/hip_runtime.h>
#include <hip/hip_bf16.h>

#define NB 32
#define NSEQ 3136
#define NDIM 64
#define NH 8
#define NAG 49
#define NPAIR 24   // K2: 23 pairs of 2 chunks + 1 triple (chunks 46,47,48)
#define K4PAIR 25  // K4: tile pairs (last block: single tile 48)

static constexpr float kScale = 0.35355339059327378f; // 8^-0.5
static constexpr float kLog2e = 1.4426950408889634f;

typedef unsigned short us;
typedef __attribute__((ext_vector_type(8))) __bf16 bf16x8;
typedef __attribute__((ext_vector_type(4))) __bf16 bf16x4;
typedef __attribute__((ext_vector_type(2))) _Float16 f16x2;
typedef __attribute__((ext_vector_type(4))) _Float16 f16x4;
typedef __attribute__((ext_vector_type(8))) _Float16 f16x8;
typedef __attribute__((ext_vector_type(4))) float f32x4;

__device__ __forceinline__ float fexp2(float x) {
#if __has_builtin(__builtin_amdgcn_exp2f)
  return __builtin_amdgcn_exp2f(x);
#else
  return exp2f(x);
#endif
}

__device__ __forceinline__ float frcp(float x) {
#if __has_builtin(__builtin_amdgcn_rcpf)
  return __builtin_amdgcn_rcpf(x);
#else
  return 1.f / x;
#endif
}

__device__ __forceinline__ unsigned pk2(float a, float b) { // pack 2 f32 -> f16x2
#if __has_builtin(__builtin_amdgcn_cvt_pkrtz)
  return __builtin_bit_cast(unsigned, __builtin_amdgcn_cvt_pkrtz(a, b));
#else
  f16x2 v = {(_Float16)a, (_Float16)b};
  return __builtin_bit_cast(unsigned, v);
#endif
}

__device__ __forceinline__ bf16x8 ldw8(const float* W, int row, int c0, int ld) {
  const float4* p = (const float4*)(W + (size_t)row * ld + c0);
  float4 v0 = p[0], v1 = p[1];
  bf16x8 r;
  r[0]=(__bf16)v0.x; r[1]=(__bf16)v0.y; r[2]=(__bf16)v0.z; r[3]=(__bf16)v0.w;
  r[4]=(__bf16)v1.x; r[5]=(__bf16)v1.y; r[6]=(__bf16)v1.z; r[7]=(__bf16)v1.w;
  return r;
}

// ---------------------------------------------------------------------------
// K1: agent table + x1 -> bf16 (staged in stage1's fragment layout).
//   agf16[b,h,a][8] = log2e*kScale*(chunkmean(x1)) @ Wq^T   (f32 math)
//   x1bf[(b*49+a)*8 + h][tok 64][8]  bf16  (16B/lane coalesced for stage1)
// grid (49, 32), block 256.
// ---------------------------------------------------------------------------
__global__ __launch_bounds__(256) void agent_x1_kernel(
    const float* __restrict__ x1, const float* __restrict__ Wq,
    us* __restrict__ x1bf, us* __restrict__ agf16) {
  __shared__ float red[4][64];
  __shared__ float marr[64];
  const int a = blockIdx.x, b = blockIdx.y, t = threadIdx.x;
  const int i64 = t & 63, cb = t >> 6;

  // row-read: row i64, cols cb*16..+15 -> bf16 -> x1bf (two 8-col groups)
  {
    const float4* s1 = (const float4*)(x1 + ((size_t)(b * NSEQ) + a * 64 + i64) * NDIM + cb * 16);
    float4 v0 = s1[0], v1 = s1[1], v2 = s1[2], v3 = s1[3];
    bf16x8 p0, p1;
    p0[0]=(__bf16)v0.x; p0[1]=(__bf16)v0.y; p0[2]=(__bf16)v0.z; p0[3]=(__bf16)v0.w;
    p0[4]=(__bf16)v1.x; p0[5]=(__bf16)v1.y; p0[6]=(__bf16)v1.z; p0[7]=(__bf16)v1.w;
    p1[0]=(__bf16)v2.x; p1[1]=(__bf16)v2.y; p1[2]=(__bf16)v2.z; p1[3]=(__bf16)v2.w;
    p1[4]=(__bf16)v3.x; p1[5]=(__bf16)v3.y; p1[6]=(__bf16)v3.z; p1[7]=(__bf16)v3.w;
    __bf16* dst = (__bf16*)x1bf;
    *(bf16x8*)(dst + ((((size_t)b * NAG + a) * 8 + cb * 2) * 64 + i64) * 8) = p0;
    *(bf16x8*)(dst + ((((size_t)b * NAG + a) * 8 + cb * 2 + 1) * 64 + i64) * 8) = p1;
  }
  // x1 column partial sums (coalesced; L1/L2 hit after the row-read)
  {
    const float* xc = x1 + ((size_t)(b * NSEQ) + a * 64 + cb * 16) * NDIM + i64;
    float cs = 0.f;
#pragma unroll
    for (int i = 0; i < 16; ++i) cs += xc[i * NDIM];
    red[cb][i64] = cs;
  }
  __syncthreads();
  if (t < 64) marr[t] = red[0][t] + red[1][t] + red[2][t] + red[3][t];
  __syncthreads();
  if (t < 64) {
    const float4* wqr = (const float4*)(Wq + (size_t)t * NDIM);
    const float4* mm = (const float4*)marr;
    float s0 = 0.f;
#pragma unroll
    for (int i = 0; i < 16; ++i) {
      float4 wv4 = wqr[i], m4 = mm[i];
      s0 += wv4.x * m4.x + wv4.y * m4.y + wv4.z * m4.z + wv4.w * m4.w;
    }
    const float val = s0 * (kScale * kLog2e / 64.f);
    ((_Float16*)agf16)[(((size_t)b * NH + (t >> 3)) * NAG + a) * 8 + (t & 7)] =
        (_Float16)val;
  }
}

// ---------------------------------------------------------------------------
// K2: fused kv-GEMM + stage-0 attention; 2 chunks/block (last pair: 3) with
// in-register PV accumulation across chunks. grid (24, 32) = 768 blocks =
// EXACTLY 3 blocks/CU x 256 CUs -> single dispatch round, no tail.
// Partials stored ONCE as f16 to pvp[bh][pair 24][441].
// ---------------------------------------------------------------------------
__global__ __launch_bounds__(256) void kv_stage0_kernel(
    const float* __restrict__ x2, const float* __restrict__ Wk,
    const float* __restrict__ Wv, const us* __restrict__ agf16,
    us* __restrict__ pvp) {
  __shared__ __align__(16) __bf16 xb[64][72];        // 9216
  __shared__ __align__(16) _Float16 klds[4][64][24]; // 12288 [wave][tok][feat16+pad]
  __shared__ __align__(16) _Float16 vlds[4][18][72]; // 10368 [wave][feat16|ones][tok]
  __shared__ __align__(16) _Float16 plds[4][64][40]; // 20480 [wave][agent][tok32+pad]
  const int pair = blockIdx.x, b = blockIdx.y, t = threadIdx.x;
  const int i64 = t & 63, cb = t >> 6;
  const int w = cb, lr = (t >> 4) & 3, lc = t & 15;
  const int nch = (pair == NPAIR - 1) ? 3 : 2;

  // weight A-frags inline-converted from f32 (L2-resident after first blocks)
  bf16x8 ak0 = ldw8(Wk, w * 16 + lc, lr * 8, NDIM);
  bf16x8 ak1 = ldw8(Wk, w * 16 + lc, 32 + lr * 8, NDIM);
  bf16x8 av0 = ldw8(Wv, w * 16 + lc, lr * 8, NDIM);
  bf16x8 av1 = ldw8(Wv, w * 16 + lc, 32 + lr * 8, NDIM);

  // agent B-frags for this wave's two heads (zero for k>=8: pad-kill); once
  const size_t bh0 = (size_t)b * NH + 2 * w;
  f16x8 ba[2][4];
#pragma unroll
  for (int hh = 0; hh < 2; ++hh)
#pragma unroll
    for (int at = 0; at < 4; ++at) {
      f16x8 v = (f16x8)(_Float16)0.0f;
      if (lr == 0) {
        int row = at * 16 + lc; if (row > 48) row = 48;
        v = *(const f16x8*)(agf16 + (bh0 + hh) * (NAG * 8) + row * 8);
      }
      ba[hh][at] = v;
    }
  vlds[w][16][i64] = (_Float16)1.0f; // ones row -> denominator column (persists)

  f32x4 accPV[2][4];
#pragma unroll
  for (int hh = 0; hh < 2; ++hh)
#pragma unroll
    for (int i = 0; i < 4; ++i) accPV[hh][i] = (f32x4){0.f, 0.f, 0.f, 0.f};

  for (int cc = 0; cc < nch; ++cc) {
    const int a = pair * 2 + cc; // last pair: 46,47,48
    if (cc) __syncthreads(); // all waves done reading xb of prev chunk

    // stage x2 tile as bf16 (thread: one row, 16 cols)
    {
      const float4* s2 = (const float4*)(x2 + ((size_t)(b * NSEQ) + a * 64 + i64) * NDIM + cb * 16);
      float4 v0 = s2[0], v1 = s2[1], v2 = s2[2], v3 = s2[3];
      bf16x8 p0, p1;
      p0[0]=(__bf16)v0.x; p0[1]=(__bf16)v0.y; p0[2]=(__bf16)v0.z; p0[3]=(__bf16)v0.w;
      p0[4]=(__bf16)v1.x; p0[5]=(__bf16)v1.y; p0[6]=(__bf16)v1.z; p0[7]=(__bf16)v1.w;
      p1[0]=(__bf16)v2.x; p1[1]=(__bf16)v2.y; p1[2]=(__bf16)v2.z; p1[3]=(__bf16)v2.w;
      p1[4]=(__bf16)v3.x; p1[5]=(__bf16)v3.y; p1[6]=(__bf16)v3.z; p1[7]=(__bf16)v3.w;
      *(bf16x8*)&xb[i64][cb * 16] = p0; *(bf16x8*)&xb[i64][cb * 16 + 8] = p1;
    }
    __syncthreads();

    // kv^T GEMM: wave w = feats w*16..+15
    f32x4 acck[4], accv[4];
#pragma unroll
    for (int i = 0; i < 4; ++i) {
      acck[i] = (f32x4){0.f, 0.f, 0.f, 0.f};
      accv[i] = (f32x4){0.f, 0.f, 0.f, 0.f};
    }
#pragma unroll
    for (int nt = 0; nt < 4; ++nt) {
      bf16x8 x0 = *(const bf16x8*)&xb[nt * 16 + lc][lr * 8];
      bf16x8 x1f = *(const bf16x8*)&xb[nt * 16 + lc][32 + lr * 8];
      acck[nt] = __builtin_amdgcn_mfma_f32_16x16x32_bf16(ak0, x0, acck[nt], 0, 0, 0);
      acck[nt] = __builtin_amdgcn_mfma_f32_16x16x32_bf16(ak1, x1f, acck[nt], 0, 0, 0);
      accv[nt] = __builtin_amdgcn_mfma_f32_16x16x32_bf16(av0, x0, accv[nt], 0, 0, 0);
      accv[nt] = __builtin_amdgcn_mfma_f32_16x16x32_bf16(av1, x1f, accv[nt], 0, 0, 0);
    }
    // wave-private relayout (no barriers; same-wave produce->consume).
#pragma unroll
    for (int nt = 0; nt < 4; ++nt) {
      f16x4 pk4;
      pk4[0]=(_Float16)acck[nt][0]; pk4[1]=(_Float16)acck[nt][1];
      pk4[2]=(_Float16)acck[nt][2]; pk4[3]=(_Float16)acck[nt][3];
      *(f16x4*)&klds[w][nt * 16 + lc][lr * 4] = pk4;
#pragma unroll
      for (int j = 0; j < 4; ++j)
        vlds[w][lr * 4 + j][nt * 16 + lc] = (_Float16)accv[nt][j];
    }

#pragma unroll
    for (int hh = 0; hh < 2; ++hh) {
#pragma unroll
      for (int half = 0; half < 2; ++half) {
        // S for 32 tokens: A = k[tok][feat(8 real)], B = agents
#pragma unroll
        for (int tb = 0; tb < 2; ++tb) {
          const int tokbase = half * 32 + tb * 16;
          f16x8 kf = *(const f16x8*)&klds[w][tokbase + lc][hh * 8];
#pragma unroll
          for (int at = 0; at < 4; ++at) {
            f32x4 sc = __builtin_amdgcn_mfma_f32_16x16x32_f16(
                kf, ba[hh][at], (f32x4){0.f, 0.f, 0.f, 0.f}, 0, 0, 0);
            // C: row = tok tb*16+lr*4+j (in-half), col = agent at*16+lc
            unsigned u0 = pk2(fexp2(sc[0]), fexp2(sc[1]));
            unsigned u1 = pk2(fexp2(sc[2]), fexp2(sc[3]));
            unsigned long long q = ((unsigned long long)u1 << 32) | u0;
            *(unsigned long long*)&plds[w][at * 16 + lc][tb * 16 + lr * 4] = q;
          }
        }
        // PV over these 32 tokens: A = P[agent][tok], B = V'[tok][feat|ones]
        const int frow = (lc < 8) ? hh * 8 + lc : 16;
        f16x8 vf = *(const f16x8*)&vlds[w][frow][half * 32 + lr * 8];
#pragma unroll
        for (int at = 0; at < 4; ++at) {
          f16x8 pf = *(const f16x8*)&plds[w][at * 16 + lc][lr * 8];
          accPV[hh][at] =
              __builtin_amdgcn_mfma_f32_16x16x32_f16(pf, vf, accPV[hh][at], 0, 0, 0);
        }
      }
    }
  }

  // store pair-partials ONCE (f16): C row = agent at*16+lr*4+j, col = feat lc
#pragma unroll
  for (int hh = 0; hh < 2; ++hh) {
    if (lc < 9) {
      _Float16* dst = (_Float16*)pvp + ((bh0 + hh) * NPAIR + pair) * 441;
#pragma unroll
      for (int at = 0; at < 4; ++at)
#pragma unroll
        for (int j = 0; j < 4; ++j) {
          const int ag = at * 16 + lr * 4 + j;
          if (ag < NAG) dst[ag * 9 + lc] = (_Float16)accPV[hh][at][j];
        }
    }
  }
}

// ---------------------------------------------------------------------------
// K3: sum 24 pair-partials (contiguous f16 21KB per bh), normalize, emit
// transposed PV table pvtF[b,h][feat 16][agent 64] f16 (feat 8 = ones).
// grid (NH, NB), block 256.
// ---------------------------------------------------------------------------
__global__ __launch_bounds__(256) void aofin_kernel(
    const us* __restrict__ pvp, us* __restrict__ pvtF) {
  __shared__ float acc[441];
  const int h = blockIdx.x, b = blockIdx.y, t = threadIdx.x;
  const size_t bh = (size_t)b * NH + h;
  const _Float16* src = (const _Float16*)pvp + bh * (NPAIR * 441);
  for (int s = t; s < 441; s += 256) {
    float v = 0.f;
#pragma unroll 6
    for (int p = 0; p < NPAIR; ++p) v += (float)src[(size_t)p * 441 + s];
    acc[s] = v;
  }
  __syncthreads();
  if (t < 64) {
    us* col = pvtF + bh * 1024 + t;
    float inv = (t < NAG) ? frcp(acc[t * 9 + 8]) : 0.f;
#pragma unroll
    for (int f = 0; f < 8; ++f) {
      float val = (t < NAG) ? acc[t * 9 + f] * inv : 0.f;
      _Float16 hv = (_Float16)val;
      col[f * 64] = __builtin_bit_cast(us, hv);
    }
    col[8 * 64] = (t < NAG) ? (us)0x3C00 : (us)0;
#pragma unroll
    for (int f = 9; f < 16; ++f) col[f * 64] = 0;
  }
}

// ---------------------------------------------------------------------------
// K4: stage-1 attention (MFMA) + output linear, fused. TILE-PAIRED:
// grid (25, 32) = 800 blocks <= 1024 concurrent (4 blocks/CU) -> single
// dispatch round, wqf/ba/pvB setup amortized over 2 tiles. Per-tile body is
// identical to the verified r15 kernel (pW stride 72, swapped-PV, hoisted qf,
// re-pipelined epilogue; wof/bias loaded per-tile to keep the VGPR envelope).
// block 512 (8 waves; wave w = head w).
// ---------------------------------------------------------------------------
__global__ __launch_bounds__(512, 8) void stage1_out_kernel(
    const us* __restrict__ x1bf, const float* __restrict__ Wq,
    const us* __restrict__ agf16, const us* __restrict__ pvtF,
    const float* __restrict__ Wo, const float* __restrict__ bo,
    float* __restrict__ out) {
  __shared__ __align__(16) __bf16 xa[64][72];      // 9216
  __shared__ __align__(16) us qcat[64][72];        // 9216 (q f16, then catL bf16)
  __shared__ __align__(16) _Float16 pW[8][16][72]; // 18432 per-wave P tiles
  const int pairx = blockIdx.x, b = blockIdx.y;
  const int t = threadIdx.x, tokl = t & 63, h = t >> 6;
  const int w = h, lane = t & 63, lr = (lane >> 4) & 3, lc = lane & 15;
  const int mtile = w & 3, thalf = w >> 2;
  const size_t bh = (size_t)b * NH + w;

  // q-weight frags inline from f32 (amortized over both tiles)
  bf16x8 wqf0 = ldw8(Wq, mtile * 16 + lc, lr * 8, NDIM);
  bf16x8 wqf1 = ldw8(Wq, mtile * 16 + lc, 32 + lr * 8, NDIM);

  // agent-table MFMA frags (ONCE per wave; amortized)
  f16x8 ba[4];
#pragma unroll
  for (int at = 0; at < 4; ++at) {
    f16x8 v = (f16x8)(_Float16)0.0f;
    if (lr == 0) {
      int row = at * 16 + lc; if (row > 48) row = 48;
      v = *(const f16x8*)(agf16 + bh * (NAG * 8) + row * 8);
    }
    ba[at] = v;
  }
  // pvt frags: A[m=feat lc][k=agent lr*8+i] (agents 32.. in pvB1; amortized)
  const us* pvb = pvtF + bh * 1024;
  f16x8 pvB0 = *(const f16x8*)(pvb + lc * 64 + lr * 8);
  f16x8 pvB1 = *(const f16x8*)(pvb + lc * 64 + 32 + lr * 8);

  for (int tt = 0; tt < 2; ++tt) {
    const int tile = pairx * 2 + tt;
    if (tile >= NAG) break;
    if (tt) __syncthreads(); // prior tile's epilogue reads of xa/qcat done

    // stage x1 tile from x1bf (16B/lane, fully coalesced)
    {
      bf16x8 p = *(const bf16x8*)((const __bf16*)x1bf +
          ((((size_t)b * NAG + tile) * 8 + h) * 64 + tokl) * 8);
      *(bf16x8*)&xa[tokl][h * 8] = p;
    }
    __syncthreads();

    // q^T = Wq @ x1^T -> qcat as f16
    {
      f32x4 aq[2];
      aq[0] = (f32x4){0.f,0.f,0.f,0.f}; aq[1] = (f32x4){0.f,0.f,0.f,0.f};
#pragma unroll
      for (int nt = 0; nt < 2; ++nt) {
        bf16x8 bx0 = *(const bf16x8*)&xa[thalf * 32 + nt * 16 + lc][lr * 8];
        bf16x8 bx1 = *(const bf16x8*)&xa[thalf * 32 + nt * 16 + lc][32 + lr * 8];
        aq[nt] = __builtin_amdgcn_mfma_f32_16x16x32_bf16(wqf0, bx0, aq[nt], 0, 0, 0);
        aq[nt] = __builtin_amdgcn_mfma_f32_16x16x32_bf16(wqf1, bx1, aq[nt], 0, 0, 0);
      }
#pragma unroll
      for (int nt = 0; nt < 2; ++nt) {
        f16x4 pk;
        pk[0]=(_Float16)aq[nt][0]; pk[1]=(_Float16)aq[nt][1];
        pk[2]=(_Float16)aq[nt][2]; pk[3]=(_Float16)aq[nt][3];
        *(f16x4*)&qcat[thalf * 32 + nt * 16 + lc][mtile * 16 + lr * 4] = pk;
      }
    }
    __syncthreads();

    // stage-1 attention via MFMA; wave w handles head w only.
    {
      _Float16* psw = &pW[w][0][0];
      // hoist ALL group q-frags (rows disjoint from catL writes)
      f16x8 qf[4];
#pragma unroll
      for (int g = 0; g < 4; ++g) qf[g] = *(const f16x8*)&qcat[g * 16 + lc][w * 8];
#pragma unroll
      for (int g = 0; g < 4; ++g) {
        // S = mfma(agents, q): C col = tok lc, rows = agents at*16+lr*4+j
#pragma unroll
        for (int at = 0; at < 4; ++at) {
          f32x4 sc = __builtin_amdgcn_mfma_f32_16x16x32_f16(
              ba[at], qf[g], (f32x4){0.f, 0.f, 0.f, 0.f}, 0, 0, 0);
          unsigned u0 = pk2(fexp2(sc[0]), fexp2(sc[1]));
          unsigned u1 = pk2(fexp2(sc[2]), fexp2(sc[3]));
          unsigned long long qq = ((unsigned long long)u1 << 32) | u0;
          *(unsigned long long*)&psw[(size_t)lc * 72 + at * 16 + lr * 4] = qq;
        }
        // P B-frags: B[k=agent lr*8+i][n=tok lc] = pW[tok][agent] rows
        f16x8 pA0 = *(const f16x8*)&psw[(size_t)lc * 72 + lr * 8];
        f16x8 pA1 = *(const f16x8*)&psw[(size_t)lc * 72 + 32 + lr * 8];
        // PV swapped: A = pvt[feat][agent], B = P^T -> C col = tok, row = feat
        f32x4 pv = __builtin_amdgcn_mfma_f32_16x16x32_f16(
            pvB0, pA0, (f32x4){0.f, 0.f, 0.f, 0.f}, 0, 0, 0);
        pv = __builtin_amdgcn_mfma_f32_16x16x32_f16(pvB1, pA1, pv, 0, 0, 0);
        // feat row 8 (denominator) lives in lane 32+lc, reg 0
        float den = __shfl(pv[0], 32 + lc);
        float inv = frcp(den);
        if (lr < 2) { // feats lr*4..+3 (0..7 real)
          bf16x4 pc;
          pc[0] = (__bf16)(pv[0] * inv); pc[1] = (__bf16)(pv[1] * inv);
          pc[2] = (__bf16)(pv[2] * inv); pc[3] = (__bf16)(pv[3] * inv);
          *(bf16x4*)((__bf16*)&qcat[g * 16 + lc][0] + w * 8 + lr * 4) = pc;
        }
      }
    }

    // xa-half of out-GEMM + Wo/bias loads: barrier-wait slack (per-tile to
    // keep VGPR envelope identical to r15 -- no spill)
    bf16x8 wof0 = ldw8(Wo, w * 16 + lc, lr * 8, 128);
    bf16x8 wof1 = ldw8(Wo, w * 16 + lc, 32 + lr * 8, 128);
    bf16x8 wof2 = ldw8(Wo, w * 16 + lc, 64 + lr * 8, 128);
    bf16x8 wof3 = ldw8(Wo, w * 16 + lc, 96 + lr * 8, 128);
    f32x4 bv = *(const f32x4*)(bo + w * 16 + lr * 4);
    f32x4 acc[4];
#pragma unroll
    for (int i = 0; i < 4; ++i) acc[i] = (f32x4){0.f,0.f,0.f,0.f};
#pragma unroll
    for (int nt = 0; nt < 4; ++nt) {
      bf16x8 b0 = *(const bf16x8*)&xa[nt * 16 + lc][lr * 8];
      bf16x8 b1 = *(const bf16x8*)&xa[nt * 16 + lc][32 + lr * 8];
      acc[nt] = __builtin_amdgcn_mfma_f32_16x16x32_bf16(wof2, b0, acc[nt], 0, 0, 0);
      acc[nt] = __builtin_amdgcn_mfma_f32_16x16x32_bf16(wof3, b1, acc[nt], 0, 0, 0);
    }
    __syncthreads();

    // catL-half + bias + direct stores (short post-barrier tail)
#pragma unroll
    for (int nt = 0; nt < 4; ++nt) {
      bf16x8 c0 = *(const bf16x8*)&qcat[nt * 16 + lc][lr * 8];
      bf16x8 c1 = *(const bf16x8*)&qcat[nt * 16 + lc][32 + lr * 8];
      acc[nt] = __builtin_amdgcn_mfma_f32_16x16x32_bf16(wof0, c0, acc[nt], 0, 0, 0);
      acc[nt] = __builtin_amdgcn_mfma_f32_16x16x32_bf16(wof1, c1, acc[nt], 0, 0, 0);
      f32x4 v = acc[nt] + bv;
      float* dst = out + ((size_t)b * NSEQ + tile * 64 + nt * 16 + lc) * 128 + w * 16 + lr * 4;
      *(f32x4*)dst = v;
    }
  }
}

extern "C" void kernel_launch(void* const* d_in, const int* in_sizes, int n_in,
                              void* d_out, int out_size, void* d_ws, size_t ws_size,
                              hipStream_t stream) {
  (void)in_sizes; (void)n_in; (void)out_size; (void)ws_size;
  const float* x1 = (const float*)d_in[0];
  const float* x2 = (const float*)d_in[1];
  const float* Wq = (const float*)d_in[2];
  const float* Wk = (const float*)d_in[3];
  const float* Wv = (const float*)d_in[4];
  const float* Wo = (const float*)d_in[5];
  const float* bo = (const float*)d_in[6];
  float* out = (float*)d_out;

  us* x1bf = (us*)d_ws;                                   // 32*3136*64 bf16 = 12.85MB
  us* agf16 = x1bf + (size_t)NB * NSEQ * 64;              // 100352 f16
  us* pvp = agf16 + (size_t)NB * NH * NAG * 8;            // 256*24*441 f16 = 5.4MB
  us* pvtF = pvp + (size_t)NB * NH * NPAIR * 441;         // 256*1024 f16
  // total ws ~= 19.3 MB

  agent_x1_kernel<<<dim3(NAG, NB), 256, 0, stream>>>(x1, Wq, x1bf, agf16);
  kv_stage0_kernel<<<dim3(NPAIR, NB), 256, 0, stream>>>(x2, Wk, Wv, agf16, pvp);
  aofin_kernel<<<dim3(NH, NB), 256, 0, stream>>>(pvp, pvtF);
  stage1_out_kernel<<<dim3(K4PAIR, NB), 512, 0, stream>>>(x1bf, Wq, agf16,
                                                          pvtF, Wo, bo, out);
}

// Round 19
// 75.205 us; speedup vs baseline: 1.4401x; 1.4401x over previous
//
#include <hip/hip_runtime.h>
#include <hip/hip_bf16.h>

#define NB 32
#define NSEQ 3136
#define NDIM 64
#define NH 8
#define NAG 49
#define NPAIR 25

static constexpr float kScale = 0.35355339059327378f; // 8^-0.5
static constexpr float kLog2e = 1.4426950408889634f;

typedef unsigned short us;
typedef __attribute__((ext_vector_type(8))) __bf16 bf16x8;
typedef __attribute__((ext_vector_type(4))) __bf16 bf16x4;
typedef __attribute__((ext_vector_type(2))) _Float16 f16x2;
typedef __attribute__((ext_vector_type(4))) _Float16 f16x4;
typedef __attribute__((ext_vector_type(8))) _Float16 f16x8;
typedef __attribute__((ext_vector_type(4))) float f32x4;

__device__ __forceinline__ float fexp2(float x) {
#if __has_builtin(__builtin_amdgcn_exp2f)
  return __builtin_amdgcn_exp2f(x);
#else
  return exp2f(x);
#endif
}

__device__ __forceinline__ float frcp(float x) {
#if __has_builtin(__builtin_amdgcn_rcpf)
  return __builtin_amdgcn_rcpf(x);
#else
  return 1.f / x;
#endif
}

__device__ __forceinline__ unsigned pk2(float a, float b) { // pack 2 f32 -> f16x2
#if __has_builtin(__builtin_amdgcn_cvt_pkrtz)
  return __builtin_bit_cast(unsigned, __builtin_amdgcn_cvt_pkrtz(a, b));
#else
  f16x2 v = {(_Float16)a, (_Float16)b};
  return __builtin_bit_cast(unsigned, v);
#endif
}

__device__ __forceinline__ bf16x8 ldw8(const float* W, int row, int c0, int ld) {
  const float4* p = (const float4*)(W + (size_t)row * ld + c0);
  float4 v0 = p[0], v1 = p[1];
  bf16x8 r;
  r[0]=(__bf16)v0.x; r[1]=(__bf16)v0.y; r[2]=(__bf16)v0.z; r[3]=(__bf16)v0.w;
  r[4]=(__bf16)v1.x; r[5]=(__bf16)v1.y; r[6]=(__bf16)v1.z; r[7]=(__bf16)v1.w;
  return r;
}

// ---------------------------------------------------------------------------
// K1: agent table + x1 -> bf16 (staged in stage1's fragment layout).
//   agf16[b,h,a][8] = log2e*kScale*(chunkmean(x1)) @ Wq^T   (f32 math)
//   x1bf[(b*49+a)*8 + h][tok 64][8]  bf16  (16B/lane coalesced for stage1)
// grid (49, 32), block 256.
// ---------------------------------------------------------------------------
__global__ __launch_bounds__(256) void agent_x1_kernel(
    const float* __restrict__ x1, const float* __restrict__ Wq,
    us* __restrict__ x1bf, us* __restrict__ agf16) {
  __shared__ float red[4][64];
  __shared__ float marr[64];
  const int a = blockIdx.x, b = blockIdx.y, t = threadIdx.x;
  const int i64 = t & 63, cb = t >> 6;

  // row-read: row i64, cols cb*16..+15 -> bf16 -> x1bf (two 8-col groups)
  {
    const float4* s1 = (const float4*)(x1 + ((size_t)(b * NSEQ) + a * 64 + i64) * NDIM + cb * 16);
    float4 v0 = s1[0], v1 = s1[1], v2 = s1[2], v3 = s1[3];
    bf16x8 p0, p1;
    p0[0]=(__bf16)v0.x; p0[1]=(__bf16)v0.y; p0[2]=(__bf16)v0.z; p0[3]=(__bf16)v0.w;
    p0[4]=(__bf16)v1.x; p0[5]=(__bf16)v1.y; p0[6]=(__bf16)v1.z; p0[7]=(__bf16)v1.w;
    p1[0]=(__bf16)v2.x; p1[1]=(__bf16)v2.y; p1[2]=(__bf16)v2.z; p1[3]=(__bf16)v2.w;
    p1[4]=(__bf16)v3.x; p1[5]=(__bf16)v3.y; p1[6]=(__bf16)v3.z; p1[7]=(__bf16)v3.w;
    __bf16* dst = (__bf16*)x1bf;
    *(bf16x8*)(dst + ((((size_t)b * NAG + a) * 8 + cb * 2) * 64 + i64) * 8) = p0;
    *(bf16x8*)(dst + ((((size_t)b * NAG + a) * 8 + cb * 2 + 1) * 64 + i64) * 8) = p1;
  }
  // x1 column partial sums (coalesced; L1/L2 hit after the row-read)
  {
    const float* xc = x1 + ((size_t)(b * NSEQ) + a * 64 + cb * 16) * NDIM + i64;
    float cs = 0.f;
#pragma unroll
    for (int i = 0; i < 16; ++i) cs += xc[i * NDIM];
    red[cb][i64] = cs;
  }
  __syncthreads();
  if (t < 64) marr[t] = red[0][t] + red[1][t] + red[2][t] + red[3][t];
  __syncthreads();
  if (t < 64) {
    const float4* wqr = (const float4*)(Wq + (size_t)t * NDIM);
    const float4* mm = (const float4*)marr;
    float s0 = 0.f;
#pragma unroll
    for (int i = 0; i < 16; ++i) {
      float4 wv4 = wqr[i], m4 = mm[i];
      s0 += wv4.x * m4.x + wv4.y * m4.y + wv4.z * m4.z + wv4.w * m4.w;
    }
    const float val = s0 * (kScale * kLog2e / 64.f);
    ((_Float16*)agf16)[(((size_t)b * NH + (t >> 3)) * NAG + a) * 8 + (t & 7)] =
        (_Float16)val;
  }
}

// ---------------------------------------------------------------------------
// K2: fused kv-GEMM + stage-0 attention; 2 chunks (128 tokens) per block with
// in-register PV accumulation across chunks. Partials stored ONCE as f16 to
// pvp[bh][pair 25][441] (contiguous for K3). No global atomics, no fences.
// grid (25, 32), block 256 (4 waves).
// ---------------------------------------------------------------------------
__global__ __launch_bounds__(256) void kv_stage0_kernel(
    const float* __restrict__ x2, const float* __restrict__ Wk,
    const float* __restrict__ Wv, const us* __restrict__ agf16,
    us* __restrict__ pvp) {
  __shared__ __align__(16) __bf16 xb[64][72];        // 9216
  __shared__ __align__(16) _Float16 klds[4][64][24]; // 12288 [wave][tok][feat16+pad]
  __shared__ __align__(16) _Float16 vlds[4][18][72]; // 10368 [wave][feat16|ones][tok]
  __shared__ __align__(16) _Float16 plds[4][64][40]; // 20480 [wave][agent][tok32+pad]
  const int pair = blockIdx.x, b = blockIdx.y, t = threadIdx.x;
  const int i64 = t & 63, cb = t >> 6;
  const int w = cb, lr = (t >> 4) & 3, lc = t & 15;

  // weight A-frags inline-converted from f32 (L2-resident after first blocks)
  bf16x8 ak0 = ldw8(Wk, w * 16 + lc, lr * 8, NDIM);
  bf16x8 ak1 = ldw8(Wk, w * 16 + lc, 32 + lr * 8, NDIM);
  bf16x8 av0 = ldw8(Wv, w * 16 + lc, lr * 8, NDIM);
  bf16x8 av1 = ldw8(Wv, w * 16 + lc, 32 + lr * 8, NDIM);

  // agent B-frags for this wave's two heads (zero for k>=8: pad-kill); once
  const size_t bh0 = (size_t)b * NH + 2 * w;
  f16x8 ba[2][4];
#pragma unroll
  for (int hh = 0; hh < 2; ++hh)
#pragma unroll
    for (int at = 0; at < 4; ++at) {
      f16x8 v = (f16x8)(_Float16)0.0f;
      if (lr == 0) {
        int row = at * 16 + lc; if (row > 48) row = 48;
        v = *(const f16x8*)(agf16 + (bh0 + hh) * (NAG * 8) + row * 8);
      }
      ba[hh][at] = v;
    }
  vlds[w][16][i64] = (_Float16)1.0f; // ones row -> denominator column (persists)

  f32x4 accPV[2][4];
#pragma unroll
  for (int hh = 0; hh < 2; ++hh)
#pragma unroll
    for (int i = 0; i < 4; ++i) accPV[hh][i] = (f32x4){0.f, 0.f, 0.f, 0.f};

  for (int cc = 0; cc < 2; ++cc) {
    const int a = pair * 2 + cc;
    if (a >= NAG) break;
    if (cc) __syncthreads(); // all waves done reading xb of prev chunk

    // stage x2 tile as bf16 (thread: one row, 16 cols)
    {
      const float4* s2 = (const float4*)(x2 + ((size_t)(b * NSEQ) + a * 64 + i64) * NDIM + cb * 16);
      float4 v0 = s2[0], v1 = s2[1], v2 = s2[2], v3 = s2[3];
      bf16x8 p0, p1;
      p0[0]=(__bf16)v0.x; p0[1]=(__bf16)v0.y; p0[2]=(__bf16)v0.z; p0[3]=(__bf16)v0.w;
      p0[4]=(__bf16)v1.x; p0[5]=(__bf16)v1.y; p0[6]=(__bf16)v1.z; p0[7]=(__bf16)v1.w;
      p1[0]=(__bf16)v2.x; p1[1]=(__bf16)v2.y; p1[2]=(__bf16)v2.z; p1[3]=(__bf16)v2.w;
      p1[4]=(__bf16)v3.x; p1[5]=(__bf16)v3.y; p1[6]=(__bf16)v3.z; p1[7]=(__bf16)v3.w;
      *(bf16x8*)&xb[i64][cb * 16] = p0; *(bf16x8*)&xb[i64][cb * 16 + 8] = p1;
    }
    __syncthreads();

    // kv^T GEMM: wave w = feats w*16..+15
    f32x4 acck[4], accv[4];
#pragma unroll
    for (int i = 0; i < 4; ++i) {
      acck[i] = (f32x4){0.f, 0.f, 0.f, 0.f};
      accv[i] = (f32x4){0.f, 0.f, 0.f, 0.f};
    }
#pragma unroll
    for (int nt = 0; nt < 4; ++nt) {
      bf16x8 x0 = *(const bf16x8*)&xb[nt * 16 + lc][lr * 8];
      bf16x8 x1f = *(const bf16x8*)&xb[nt * 16 + lc][32 + lr * 8];
      acck[nt] = __builtin_amdgcn_mfma_f32_16x16x32_bf16(ak0, x0, acck[nt], 0, 0, 0);
      acck[nt] = __builtin_amdgcn_mfma_f32_16x16x32_bf16(ak1, x1f, acck[nt], 0, 0, 0);
      accv[nt] = __builtin_amdgcn_mfma_f32_16x16x32_bf16(av0, x0, accv[nt], 0, 0, 0);
      accv[nt] = __builtin_amdgcn_mfma_f32_16x16x32_bf16(av1, x1f, accv[nt], 0, 0, 0);
    }
    // wave-private relayout (no barriers; same-wave produce->consume).
#pragma unroll
    for (int nt = 0; nt < 4; ++nt) {
      f16x4 pk4;
      pk4[0]=(_Float16)acck[nt][0]; pk4[1]=(_Float16)acck[nt][1];
      pk4[2]=(_Float16)acck[nt][2]; pk4[3]=(_Float16)acck[nt][3];
      *(f16x4*)&klds[w][nt * 16 + lc][lr * 4] = pk4;
#pragma unroll
      for (int j = 0; j < 4; ++j)
        vlds[w][lr * 4 + j][nt * 16 + lc] = (_Float16)accv[nt][j];
    }

#pragma unroll
    for (int hh = 0; hh < 2; ++hh) {
#pragma unroll
      for (int half = 0; half < 2; ++half) {
        // S for 32 tokens: A = k[tok][feat(8 real)], B = agents
#pragma unroll
        for (int tb = 0; tb < 2; ++tb) {
          const int tokbase = half * 32 + tb * 16;
          f16x8 kf = *(const f16x8*)&klds[w][tokbase + lc][hh * 8];
#pragma unroll
          for (int at = 0; at < 4; ++at) {
            f32x4 sc = __builtin_amdgcn_mfma_f32_16x16x32_f16(
                kf, ba[hh][at], (f32x4){0.f, 0.f, 0.f, 0.f}, 0, 0, 0);
            // C: row = tok tb*16+lr*4+j (in-half), col = agent at*16+lc
            unsigned u0 = pk2(fexp2(sc[0]), fexp2(sc[1]));
            unsigned u1 = pk2(fexp2(sc[2]), fexp2(sc[3]));
            unsigned long long q = ((unsigned long long)u1 << 32) | u0;
            *(unsigned long long*)&plds[w][at * 16 + lc][tb * 16 + lr * 4] = q;
          }
        }
        // PV over these 32 tokens: A = P[agent][tok], B = V'[tok][feat|ones]
        const int frow = (lc < 8) ? hh * 8 + lc : 16;
        f16x8 vf = *(const f16x8*)&vlds[w][frow][half * 32 + lr * 8];
#pragma unroll
        for (int at = 0; at < 4; ++at) {
          f16x8 pf = *(const f16x8*)&plds[w][at * 16 + lc][lr * 8];
          accPV[hh][at] =
              __builtin_amdgcn_mfma_f32_16x16x32_f16(pf, vf, accPV[hh][at], 0, 0, 0);
        }
      }
    }
  }

  // store pair-partials ONCE (f16): C row = agent at*16+lr*4+j, col = feat lc
#pragma unroll
  for (int hh = 0; hh < 2; ++hh) {
    if (lc < 9) {
      _Float16* dst = (_Float16*)pvp + ((bh0 + hh) * NPAIR + pair) * 441;
#pragma unroll
      for (int at = 0; at < 4; ++at)
#pragma unroll
        for (int j = 0; j < 4; ++j) {
          const int ag = at * 16 + lr * 4 + j;
          if (ag < NAG) dst[ag * 9 + lc] = (_Float16)accPV[hh][at][j];
        }
    }
  }
}

// ---------------------------------------------------------------------------
// K3: sum 25 pair-partials (contiguous f16 22KB per bh), normalize, emit
// transposed PV table pvtF[b,h][feat 16][agent 64] f16 (feat 8 = ones).
// grid (NH, NB), block 256.
// ---------------------------------------------------------------------------
__global__ __launch_bounds__(256) void aofin_kernel(
    const us* __restrict__ pvp, us* __restrict__ pvtF) {
  __shared__ float acc[441];
  const int h = blockIdx.x, b = blockIdx.y, t = threadIdx.x;
  const size_t bh = (size_t)b * NH + h;
  const _Float16* src = (const _Float16*)pvp + bh * (NPAIR * 441);
  for (int s = t; s < 441; s += 256) {
    float v = 0.f;
#pragma unroll 5
    for (int p = 0; p < NPAIR; ++p) v += (float)src[(size_t)p * 441 + s];
    acc[s] = v;
  }
  __syncthreads();
  if (t < 64) {
    us* col = pvtF + bh * 1024 + t;
    float inv = (t < NAG) ? frcp(acc[t * 9 + 8]) : 0.f;
#pragma unroll
    for (int f = 0; f < 8; ++f) {
      float val = (t < NAG) ? acc[t * 9 + f] * inv : 0.f;
      _Float16 hv = (_Float16)val;
      col[f * 64] = __builtin_bit_cast(us, hv);
    }
    col[8 * 64] = (t < NAG) ? (us)0x3C00 : (us)0;
#pragma unroll
    for (int f = 9; f < 16; ++f) col[f * 64] = 0;
  }
}

// ---------------------------------------------------------------------------
// K4: stage-1 attention (MFMA) + output linear, fused. pW stride 72 f16
// (bank-minimal). PV operands swapped (lane = 4 consecutive feats of 1 token).
// qf fragments hoisted; epilogue re-pipelined (xa-half + Wo/bias pre-barrier).
// grid (49, 32), block 512 (8 waves; wave w = head w).
// ---------------------------------------------------------------------------
__global__ __launch_bounds__(512, 8) void stage1_out_kernel(
    const us* __restrict__ x1bf, const float* __restrict__ Wq,
    const us* __restrict__ agf16, const us* __restrict__ pvtF,
    const float* __restrict__ Wo, const float* __restrict__ bo,
    float* __restrict__ out) {
  __shared__ __align__(16) __bf16 xa[64][72];      // 9216
  __shared__ __align__(16) us qcat[64][72];        // 9216 (q f16, then catL bf16)
  __shared__ __align__(16) _Float16 pW[8][16][72]; // 18432 per-wave P tiles
  const int tile = blockIdx.x, b = blockIdx.y;
  const int t = threadIdx.x, tokl = t & 63, h = t >> 6;
  const int w = h, lane = t & 63, lr = (lane >> 4) & 3, lc = lane & 15;
  const int mtile = w & 3, thalf = w >> 2;
  const size_t bh = (size_t)b * NH + w;

  // q-weight frags inline from f32
  bf16x8 wqf0 = ldw8(Wq, mtile * 16 + lc, lr * 8, NDIM);
  bf16x8 wqf1 = ldw8(Wq, mtile * 16 + lc, 32 + lr * 8, NDIM);

  // agent-table MFMA frags (ONCE per wave)
  f16x8 ba[4];
#pragma unroll
  for (int at = 0; at < 4; ++at) {
    f16x8 v = (f16x8)(_Float16)0.0f;
    if (lr == 0) {
      int row = at * 16 + lc; if (row > 48) row = 48;
      v = *(const f16x8*)(agf16 + bh * (NAG * 8) + row * 8);
    }
    ba[at] = v;
  }
  // pvt frags: A[m=feat lc][k=agent lr*8+i] (agents 32.. in pvB1)
  const us* pvb = pvtF + bh * 1024;
  f16x8 pvB0 = *(const f16x8*)(pvb + lc * 64 + lr * 8);
  f16x8 pvB1 = *(const f16x8*)(pvb + lc * 64 + 32 + lr * 8);

  // stage x1 tile from x1bf (16B/lane, fully coalesced)
  {
    bf16x8 p = *(const bf16x8*)((const __bf16*)x1bf +
        ((((size_t)b * NAG + tile) * 8 + h) * 64 + tokl) * 8);
    *(bf16x8*)&xa[tokl][h * 8] = p;
  }
  __syncthreads();

  // q^T = Wq @ x1^T -> qcat as f16
  {
    f32x4 aq[2];
    aq[0] = (f32x4){0.f,0.f,0.f,0.f}; aq[1] = (f32x4){0.f,0.f,0.f,0.f};
#pragma unroll
    for (int nt = 0; nt < 2; ++nt) {
      bf16x8 bx0 = *(const bf16x8*)&xa[thalf * 32 + nt * 16 + lc][lr * 8];
      bf16x8 bx1 = *(const bf16x8*)&xa[thalf * 32 + nt * 16 + lc][32 + lr * 8];
      aq[nt] = __builtin_amdgcn_mfma_f32_16x16x32_bf16(wqf0, bx0, aq[nt], 0, 0, 0);
      aq[nt] = __builtin_amdgcn_mfma_f32_16x16x32_bf16(wqf1, bx1, aq[nt], 0, 0, 0);
    }
#pragma unroll
    for (int nt = 0; nt < 2; ++nt) {
      f16x4 pk;
      pk[0]=(_Float16)aq[nt][0]; pk[1]=(_Float16)aq[nt][1];
      pk[2]=(_Float16)aq[nt][2]; pk[3]=(_Float16)aq[nt][3];
      *(f16x4*)&qcat[thalf * 32 + nt * 16 + lc][mtile * 16 + lr * 4] = pk;
    }
  }
  __syncthreads();

  // stage-1 attention via MFMA; wave w handles head w only.
  {
    _Float16* psw = &pW[w][0][0];
    // hoist ALL group q-frags: rows g*16+lc are never touched by catL writes
    // of other groups -> kills the false qcat WAR that serialized groups.
    f16x8 qf[4];
#pragma unroll
    for (int g = 0; g < 4; ++g) qf[g] = *(const f16x8*)&qcat[g * 16 + lc][w * 8];
#pragma unroll
    for (int g = 0; g < 4; ++g) {
      // S = mfma(agents, q): C col = tok lc, rows = agents at*16+lr*4+j
#pragma unroll
      for (int at = 0; at < 4; ++at) {
        f32x4 sc = __builtin_amdgcn_mfma_f32_16x16x32_f16(
            ba[at], qf[g], (f32x4){0.f, 0.f, 0.f, 0.f}, 0, 0, 0);
        unsigned u0 = pk2(fexp2(sc[0]), fexp2(sc[1]));
        unsigned u1 = pk2(fexp2(sc[2]), fexp2(sc[3]));
        unsigned long long qq = ((unsigned long long)u1 << 32) | u0;
        *(unsigned long long*)&psw[(size_t)lc * 72 + at * 16 + lr * 4] = qq;
      }
      // P B-frags: B[k=agent lr*8+i][n=tok lc] = pW[tok][agent] rows
      f16x8 pA0 = *(const f16x8*)&psw[(size_t)lc * 72 + lr * 8];
      f16x8 pA1 = *(const f16x8*)&psw[(size_t)lc * 72 + 32 + lr * 8];
      // PV swapped: A = pvt[feat][agent], B = P^T -> C col = tok, row = feat
      f32x4 pv = __builtin_amdgcn_mfma_f32_16x16x32_f16(
          pvB0, pA0, (f32x4){0.f, 0.f, 0.f, 0.f}, 0, 0, 0);
      pv = __builtin_amdgcn_mfma_f32_16x16x32_f16(pvB1, pA1, pv, 0, 0, 0);
      // feat row 8 (denominator) lives in lane 32+lc, reg 0
      float den = __shfl(pv[0], 32 + lc);
      float inv = frcp(den);
      if (lr < 2) { // feats lr*4..+3 (0..7 real)
        bf16x4 pc;
        pc[0] = (__bf16)(pv[0] * inv); pc[1] = (__bf16)(pv[1] * inv);
        pc[2] = (__bf16)(pv[2] * inv); pc[3] = (__bf16)(pv[3] * inv);
        *(bf16x4*)((__bf16*)&qcat[g * 16 + lc][0] + w * 8 + lr * 4) = pc;
      }
    }
  }

  // xa-half of out-GEMM + Wo/bias loads: runs in the barrier-wait slack
  // (xa stable since barrier 1; ba/pvB dead -> no VGPR-cap pressure)
  bf16x8 wof0 = ldw8(Wo, w * 16 + lc, lr * 8, 128);
  bf16x8 wof1 = ldw8(Wo, w * 16 + lc, 32 + lr * 8, 128);
  bf16x8 wof2 = ldw8(Wo, w * 16 + lc, 64 + lr * 8, 128);
  bf16x8 wof3 = ldw8(Wo, w * 16 + lc, 96 + lr * 8, 128);
  f32x4 bv = *(const f32x4*)(bo + w * 16 + lr * 4);
  f32x4 acc[4];
#pragma unroll
  for (int i = 0; i < 4; ++i) acc[i] = (f32x4){0.f,0.f,0.f,0.f};
#pragma unroll
  for (int nt = 0; nt < 4; ++nt) {
    bf16x8 b0 = *(const bf16x8*)&xa[nt * 16 + lc][lr * 8];
    bf16x8 b1 = *(const bf16x8*)&xa[nt * 16 + lc][32 + lr * 8];
    acc[nt] = __builtin_amdgcn_mfma_f32_16x16x32_bf16(wof2, b0, acc[nt], 0, 0, 0);
    acc[nt] = __builtin_amdgcn_mfma_f32_16x16x32_bf16(wof3, b1, acc[nt], 0, 0, 0);
  }
  __syncthreads();

  // catL-half + bias + direct stores (short post-barrier tail)
#pragma unroll
  for (int nt = 0; nt < 4; ++nt) {
    bf16x8 c0 = *(const bf16x8*)&qcat[nt * 16 + lc][lr * 8];
    bf16x8 c1 = *(const bf16x8*)&qcat[nt * 16 + lc][32 + lr * 8];
    acc[nt] = __builtin_amdgcn_mfma_f32_16x16x32_bf16(wof0, c0, acc[nt], 0, 0, 0);
    acc[nt] = __builtin_amdgcn_mfma_f32_16x16x32_bf16(wof1, c1, acc[nt], 0, 0, 0);
    f32x4 v = acc[nt] + bv;
    float* dst = out + ((size_t)b * NSEQ + tile * 64 + nt * 16 + lc) * 128 + w * 16 + lr * 4;
    *(f32x4*)dst = v;
  }
}

extern "C" void kernel_launch(void* const* d_in, const int* in_sizes, int n_in,
                              void* d_out, int out_size, void* d_ws, size_t ws_size,
                              hipStream_t stream) {
  (void)in_sizes; (void)n_in; (void)out_size; (void)ws_size;
  const float* x1 = (const float*)d_in[0];
  const float* x2 = (const float*)d_in[1];
  const float* Wq = (const float*)d_in[2];
  const float* Wk = (const float*)d_in[3];
  const float* Wv = (const float*)d_in[4];
  const float* Wo = (const float*)d_in[5];
  const float* bo = (const float*)d_in[6];
  float* out = (float*)d_out;

  us* x1bf = (us*)d_ws;                                   // 32*3136*64 bf16 = 12.85MB
  us* agf16 = x1bf + (size_t)NB * NSEQ * 64;              // 100352 f16
  us* pvp = agf16 + (size_t)NB * NH * NAG * 8;            // 256*25*441 f16 = 5.6MB
  us* pvtF = pvp + (size_t)NB * NH * NPAIR * 441;         // 256*1024 f16
  // total ws ~= 19.5 MB

  agent_x1_kernel<<<dim3(NAG, NB), 256, 0, stream>>>(x1, Wq, x1bf, agf16);
  kv_stage0_kernel<<<dim3(NPAIR, NB), 256, 0, stream>>>(x2, Wk, Wv, agf16, pvp);
  aofin_kernel<<<dim3(NH, NB), 256, 0, stream>>>(pvp, pvtF);
  stage1_out_kernel<<<dim3(NAG, NB), 512, 0, stream>>>(x1bf, Wq, agf16,
                                                       pvtF, Wo, bo, out);
}

// Round 20
// 72.524 us; speedup vs baseline: 1.4934x; 1.0370x over previous
//
#include <hip/hip_runtime.h>
#include <hip/hip_bf16.h>

#define NB 32
#define NSEQ 3136
#define NDIM 64
#define NH 8
#define NAG 49
#define NPAIR 24   // K2: 23 pairs of 2 chunks + 1 triple (46,47,48) = 768 blocks

static constexpr float kScale = 0.35355339059327378f; // 8^-0.5
static constexpr float kLog2e = 1.4426950408889634f;

typedef unsigned short us;
typedef __attribute__((ext_vector_type(8))) __bf16 bf16x8;
typedef __attribute__((ext_vector_type(4))) __bf16 bf16x4;
typedef __attribute__((ext_vector_type(2))) _Float16 f16x2;
typedef __attribute__((ext_vector_type(4))) _Float16 f16x4;
typedef __attribute__((ext_vector_type(8))) _Float16 f16x8;
typedef __attribute__((ext_vector_type(4))) float f32x4;

__device__ __forceinline__ float fexp2(float x) {
#if __has_builtin(__builtin_amdgcn_exp2f)
  return __builtin_amdgcn_exp2f(x);
#else
  return exp2f(x);
#endif
}

__device__ __forceinline__ float frcp(float x) {
#if __has_builtin(__builtin_amdgcn_rcpf)
  return __builtin_amdgcn_rcpf(x);
#else
  return 1.f / x;
#endif
}

__device__ __forceinline__ unsigned pk2(float a, float b) { // pack 2 f32 -> f16x2
#if __has_builtin(__builtin_amdgcn_cvt_pkrtz)
  return __builtin_bit_cast(unsigned, __builtin_amdgcn_cvt_pkrtz(a, b));
#else
  f16x2 v = {(_Float16)a, (_Float16)b};
  return __builtin_bit_cast(unsigned, v);
#endif
}

__device__ __forceinline__ bf16x8 ldw8(const float* W, int row, int c0, int ld) {
  const float4* p = (const float4*)(W + (size_t)row * ld + c0);
  float4 v0 = p[0], v1 = p[1];
  bf16x8 r;
  r[0]=(__bf16)v0.x; r[1]=(__bf16)v0.y; r[2]=(__bf16)v0.z; r[3]=(__bf16)v0.w;
  r[4]=(__bf16)v1.x; r[5]=(__bf16)v1.y; r[6]=(__bf16)v1.z; r[7]=(__bf16)v1.w;
  return r;
}

// ---------------------------------------------------------------------------
// K1: agent table + x1 -> bf16 (staged in stage1's fragment layout).
//   agf16[b,h,a][8] = log2e*kScale*(chunkmean(x1)) @ Wq^T   (f32 math)
//   x1bf[(b*49+a)*8 + h][tok 64][8]  bf16  (16B/lane coalesced for stage1)
// grid (49, 32), block 256.
// ---------------------------------------------------------------------------
__global__ __launch_bounds__(256) void agent_x1_kernel(
    const float* __restrict__ x1, const float* __restrict__ Wq,
    us* __restrict__ x1bf, us* __restrict__ agf16) {
  __shared__ float red[4][64];
  __shared__ float marr[64];
  const int a = blockIdx.x, b = blockIdx.y, t = threadIdx.x;
  const int i64 = t & 63, cb = t >> 6;

  // row-read: row i64, cols cb*16..+15 -> bf16 -> x1bf (two 8-col groups)
  {
    const float4* s1 = (const float4*)(x1 + ((size_t)(b * NSEQ) + a * 64 + i64) * NDIM + cb * 16);
    float4 v0 = s1[0], v1 = s1[1], v2 = s1[2], v3 = s1[3];
    bf16x8 p0, p1;
    p0[0]=(__bf16)v0.x; p0[1]=(__bf16)v0.y; p0[2]=(__bf16)v0.z; p0[3]=(__bf16)v0.w;
    p0[4]=(__bf16)v1.x; p0[5]=(__bf16)v1.y; p0[6]=(__bf16)v1.z; p0[7]=(__bf16)v1.w;
    p1[0]=(__bf16)v2.x; p1[1]=(__bf16)v2.y; p1[2]=(__bf16)v2.z; p1[3]=(__bf16)v2.w;
    p1[4]=(__bf16)v3.x; p1[5]=(__bf16)v3.y; p1[6]=(__bf16)v3.z; p1[7]=(__bf16)v3.w;
    __bf16* dst = (__bf16*)x1bf;
    *(bf16x8*)(dst + ((((size_t)b * NAG + a) * 8 + cb * 2) * 64 + i64) * 8) = p0;
    *(bf16x8*)(dst + ((((size_t)b * NAG + a) * 8 + cb * 2 + 1) * 64 + i64) * 8) = p1;
  }
  // x1 column partial sums (coalesced; L1/L2 hit after the row-read)
  {
    const float* xc = x1 + ((size_t)(b * NSEQ) + a * 64 + cb * 16) * NDIM + i64;
    float cs = 0.f;
#pragma unroll
    for (int i = 0; i < 16; ++i) cs += xc[i * NDIM];
    red[cb][i64] = cs;
  }
  __syncthreads();
  if (t < 64) marr[t] = red[0][t] + red[1][t] + red[2][t] + red[3][t];
  __syncthreads();
  if (t < 64) {
    const float4* wqr = (const float4*)(Wq + (size_t)t * NDIM);
    const float4* mm = (const float4*)marr;
    float s0 = 0.f;
#pragma unroll
    for (int i = 0; i < 16; ++i) {
      float4 wv4 = wqr[i], m4 = mm[i];
      s0 += wv4.x * m4.x + wv4.y * m4.y + wv4.z * m4.z + wv4.w * m4.w;
    }
    const float val = s0 * (kScale * kLog2e / 64.f);
    ((_Float16*)agf16)[(((size_t)b * NH + (t >> 3)) * NAG + a) * 8 + (t & 7)] =
        (_Float16)val;
  }
}

// ---------------------------------------------------------------------------
// K2: fused kv-GEMM + stage-0 attention; 2 chunks/block (last pair: 3) with
// in-register PV accumulation across chunks. grid (24, 32) = 768 blocks =
// EXACTLY 3 blocks/CU x 256 CUs -> single dispatch round, no tail.
// Partials stored ONCE as f16 to pvp[bh][pair 24][441]. No atomics/fences.
// ---------------------------------------------------------------------------
__global__ __launch_bounds__(256) void kv_stage0_kernel(
    const float* __restrict__ x2, const float* __restrict__ Wk,
    const float* __restrict__ Wv, const us* __restrict__ agf16,
    us* __restrict__ pvp) {
  __shared__ __align__(16) __bf16 xb[64][72];        // 9216
  __shared__ __align__(16) _Float16 klds[4][64][24]; // 12288 [wave][tok][feat16+pad]
  __shared__ __align__(16) _Float16 vlds[4][18][72]; // 10368 [wave][feat16|ones][tok]
  __shared__ __align__(16) _Float16 plds[4][64][40]; // 20480 [wave][agent][tok32+pad]
  const int pair = blockIdx.x, b = blockIdx.y, t = threadIdx.x;
  const int i64 = t & 63, cb = t >> 6;
  const int w = cb, lr = (t >> 4) & 3, lc = t & 15;
  const int nch = (pair == NPAIR - 1) ? 3 : 2;

  // weight A-frags inline-converted from f32 (L2-resident after first blocks)
  bf16x8 ak0 = ldw8(Wk, w * 16 + lc, lr * 8, NDIM);
  bf16x8 ak1 = ldw8(Wk, w * 16 + lc, 32 + lr * 8, NDIM);
  bf16x8 av0 = ldw8(Wv, w * 16 + lc, lr * 8, NDIM);
  bf16x8 av1 = ldw8(Wv, w * 16 + lc, 32 + lr * 8, NDIM);

  // agent B-frags for this wave's two heads (zero for k>=8: pad-kill); once
  const size_t bh0 = (size_t)b * NH + 2 * w;
  f16x8 ba[2][4];
#pragma unroll
  for (int hh = 0; hh < 2; ++hh)
#pragma unroll
    for (int at = 0; at < 4; ++at) {
      f16x8 v = (f16x8)(_Float16)0.0f;
      if (lr == 0) {
        int row = at * 16 + lc; if (row > 48) row = 48;
        v = *(const f16x8*)(agf16 + (bh0 + hh) * (NAG * 8) + row * 8);
      }
      ba[hh][at] = v;
    }
  vlds[w][16][i64] = (_Float16)1.0f; // ones row -> denominator column (persists)

  f32x4 accPV[2][4];
#pragma unroll
  for (int hh = 0; hh < 2; ++hh)
#pragma unroll
    for (int i = 0; i < 4; ++i) accPV[hh][i] = (f32x4){0.f, 0.f, 0.f, 0.f};

  for (int cc = 0; cc < nch; ++cc) {
    const int a = pair * 2 + cc; // last pair: 46,47,48
    if (cc) __syncthreads(); // all waves done reading xb of prev chunk

    // stage x2 tile as bf16 (thread: one row, 16 cols)
    {
      const float4* s2 = (const float4*)(x2 + ((size_t)(b * NSEQ) + a * 64 + i64) * NDIM + cb * 16);
      float4 v0 = s2[0], v1 = s2[1], v2 = s2[2], v3 = s2[3];
      bf16x8 p0, p1;
      p0[0]=(__bf16)v0.x; p0[1]=(__bf16)v0.y; p0[2]=(__bf16)v0.z; p0[3]=(__bf16)v0.w;
      p0[4]=(__bf16)v1.x; p0[5]=(__bf16)v1.y; p0[6]=(__bf16)v1.z; p0[7]=(__bf16)v1.w;
      p1[0]=(__bf16)v2.x; p1[1]=(__bf16)v2.y; p1[2]=(__bf16)v2.z; p1[3]=(__bf16)v2.w;
      p1[4]=(__bf16)v3.x; p1[5]=(__bf16)v3.y; p1[6]=(__bf16)v3.z; p1[7]=(__bf16)v3.w;
      *(bf16x8*)&xb[i64][cb * 16] = p0; *(bf16x8*)&xb[i64][cb * 16 + 8] = p1;
    }
    __syncthreads();

    // kv^T GEMM: wave w = feats w*16..+15
    f32x4 acck[4], accv[4];
#pragma unroll
    for (int i = 0; i < 4; ++i) {
      acck[i] = (f32x4){0.f, 0.f, 0.f, 0.f};
      accv[i] = (f32x4){0.f, 0.f, 0.f, 0.f};
    }
#pragma unroll
    for (int nt = 0; nt < 4; ++nt) {
      bf16x8 x0 = *(const bf16x8*)&xb[nt * 16 + lc][lr * 8];
      bf16x8 x1f = *(const bf16x8*)&xb[nt * 16 + lc][32 + lr * 8];
      acck[nt] = __builtin_amdgcn_mfma_f32_16x16x32_bf16(ak0, x0, acck[nt], 0, 0, 0);
      acck[nt] = __builtin_amdgcn_mfma_f32_16x16x32_bf16(ak1, x1f, acck[nt], 0, 0, 0);
      accv[nt] = __builtin_amdgcn_mfma_f32_16x16x32_bf16(av0, x0, accv[nt], 0, 0, 0);
      accv[nt] = __builtin_amdgcn_mfma_f32_16x16x32_bf16(av1, x1f, accv[nt], 0, 0, 0);
    }
    // wave-private relayout (no barriers; same-wave produce->consume).
#pragma unroll
    for (int nt = 0; nt < 4; ++nt) {
      f16x4 pk4;
      pk4[0]=(_Float16)acck[nt][0]; pk4[1]=(_Float16)acck[nt][1];
      pk4[2]=(_Float16)acck[nt][2]; pk4[3]=(_Float16)acck[nt][3];
      *(f16x4*)&klds[w][nt * 16 + lc][lr * 4] = pk4;
#pragma unroll
      for (int j = 0; j < 4; ++j)
        vlds[w][lr * 4 + j][nt * 16 + lc] = (_Float16)accv[nt][j];
    }

#pragma unroll
    for (int hh = 0; hh < 2; ++hh) {
#pragma unroll
      for (int half = 0; half < 2; ++half) {
        // S for 32 tokens: A = k[tok][feat(8 real)], B = agents
#pragma unroll
        for (int tb = 0; tb < 2; ++tb) {
          const int tokbase = half * 32 + tb * 16;
          f16x8 kf = *(const f16x8*)&klds[w][tokbase + lc][hh * 8];
#pragma unroll
          for (int at = 0; at < 4; ++at) {
            f32x4 sc = __builtin_amdgcn_mfma_f32_16x16x32_f16(
                kf, ba[hh][at], (f32x4){0.f, 0.f, 0.f, 0.f}, 0, 0, 0);
            // C: row = tok tb*16+lr*4+j (in-half), col = agent at*16+lc
            unsigned u0 = pk2(fexp2(sc[0]), fexp2(sc[1]));
            unsigned u1 = pk2(fexp2(sc[2]), fexp2(sc[3]));
            unsigned long long q = ((unsigned long long)u1 << 32) | u0;
            *(unsigned long long*)&plds[w][at * 16 + lc][tb * 16 + lr * 4] = q;
          }
        }
        // PV over these 32 tokens: A = P[agent][tok], B = V'[tok][feat|ones]
        const int frow = (lc < 8) ? hh * 8 + lc : 16;
        f16x8 vf = *(const f16x8*)&vlds[w][frow][half * 32 + lr * 8];
#pragma unroll
        for (int at = 0; at < 4; ++at) {
          f16x8 pf = *(const f16x8*)&plds[w][at * 16 + lc][lr * 8];
          accPV[hh][at] =
              __builtin_amdgcn_mfma_f32_16x16x32_f16(pf, vf, accPV[hh][at], 0, 0, 0);
        }
      }
    }
  }

  // store pair-partials ONCE (f16): C row = agent at*16+lr*4+j, col = feat lc
#pragma unroll
  for (int hh = 0; hh < 2; ++hh) {
    if (lc < 9) {
      _Float16* dst = (_Float16*)pvp + ((bh0 + hh) * NPAIR + pair) * 441;
#pragma unroll
      for (int at = 0; at < 4; ++at)
#pragma unroll
        for (int j = 0; j < 4; ++j) {
          const int ag = at * 16 + lr * 4 + j;
          if (ag < NAG) dst[ag * 9 + lc] = (_Float16)accPV[hh][at][j];
        }
    }
  }
}

// ---------------------------------------------------------------------------
// K3: sum 24 pair-partials (contiguous f16 21KB per bh), normalize, emit
// transposed PV table pvtF[b,h][feat 16][agent 64] f16 (feat 8 = ones).
// grid (NH, NB), block 256.
// ---------------------------------------------------------------------------
__global__ __launch_bounds__(256) void aofin_kernel(
    const us* __restrict__ pvp, us* __restrict__ pvtF) {
  __shared__ float acc[441];
  const int h = blockIdx.x, b = blockIdx.y, t = threadIdx.x;
  const size_t bh = (size_t)b * NH + h;
  const _Float16* src = (const _Float16*)pvp + bh * (NPAIR * 441);
  for (int s = t; s < 441; s += 256) {
    float v = 0.f;
#pragma unroll 6
    for (int p = 0; p < NPAIR; ++p) v += (float)src[(size_t)p * 441 + s];
    acc[s] = v;
  }
  __syncthreads();
  if (t < 64) {
    us* col = pvtF + bh * 1024 + t;
    float inv = (t < NAG) ? frcp(acc[t * 9 + 8]) : 0.f;
#pragma unroll
    for (int f = 0; f < 8; ++f) {
      float val = (t < NAG) ? acc[t * 9 + f] * inv : 0.f;
      _Float16 hv = (_Float16)val;
      col[f * 64] = __builtin_bit_cast(us, hv);
    }
    col[8 * 64] = (t < NAG) ? (us)0x3C00 : (us)0;
#pragma unroll
    for (int f = 9; f < 16; ++f) col[f * 64] = 0;
  }
}

// ---------------------------------------------------------------------------
// K4: stage-1 attention (MFMA) + output linear, fused. pW stride 72 f16
// (bank-minimal). PV operands swapped (lane = 4 consecutive feats of 1 token).
// qf fragments hoisted; epilogue re-pipelined (xa-half + Wo/bias pre-barrier).
// BYTE-IDENTICAL to the verified r15/r17/r19 kernel (75.2 us state).
// grid (49, 32), block 512 (8 waves; wave w = head w).
// ---------------------------------------------------------------------------
__global__ __launch_bounds__(512, 8) void stage1_out_kernel(
    const us* __restrict__ x1bf, const float* __restrict__ Wq,
    const us* __restrict__ agf16, const us* __restrict__ pvtF,
    const float* __restrict__ Wo, const float* __restrict__ bo,
    float* __restrict__ out) {
  __shared__ __align__(16) __bf16 xa[64][72];      // 9216
  __shared__ __align__(16) us qcat[64][72];        // 9216 (q f16, then catL bf16)
  __shared__ __align__(16) _Float16 pW[8][16][72]; // 18432 per-wave P tiles
  const int tile = blockIdx.x, b = blockIdx.y;
  const int t = threadIdx.x, tokl = t & 63, h = t >> 6;
  const int w = h, lane = t & 63, lr = (lane >> 4) & 3, lc = lane & 15;
  const int mtile = w & 3, thalf = w >> 2;
  const size_t bh = (size_t)b * NH + w;

  // q-weight frags inline from f32
  bf16x8 wqf0 = ldw8(Wq, mtile * 16 + lc, lr * 8, NDIM);
  bf16x8 wqf1 = ldw8(Wq, mtile * 16 + lc, 32 + lr * 8, NDIM);

  // agent-table MFMA frags (ONCE per wave)
  f16x8 ba[4];
#pragma unroll
  for (int at = 0; at < 4; ++at) {
    f16x8 v = (f16x8)(_Float16)0.0f;
    if (lr == 0) {
      int row = at * 16 + lc; if (row > 48) row = 48;
      v = *(const f16x8*)(agf16 + bh * (NAG * 8) + row * 8);
    }
    ba[at] = v;
  }
  // pvt frags: A[m=feat lc][k=agent lr*8+i] (agents 32.. in pvB1)
  const us* pvb = pvtF + bh * 1024;
  f16x8 pvB0 = *(const f16x8*)(pvb + lc * 64 + lr * 8);
  f16x8 pvB1 = *(const f16x8*)(pvb + lc * 64 + 32 + lr * 8);

  // stage x1 tile from x1bf (16B/lane, fully coalesced)
  {
    bf16x8 p = *(const bf16x8*)((const __bf16*)x1bf +
        ((((size_t)b * NAG + tile) * 8 + h) * 64 + tokl) * 8);
    *(bf16x8*)&xa[tokl][h * 8] = p;
  }
  __syncthreads();

  // q^T = Wq @ x1^T -> qcat as f16
  {
    f32x4 aq[2];
    aq[0] = (f32x4){0.f,0.f,0.f,0.f}; aq[1] = (f32x4){0.f,0.f,0.f,0.f};
#pragma unroll
    for (int nt = 0; nt < 2; ++nt) {
      bf16x8 bx0 = *(const bf16x8*)&xa[thalf * 32 + nt * 16 + lc][lr * 8];
      bf16x8 bx1 = *(const bf16x8*)&xa[thalf * 32 + nt * 16 + lc][32 + lr * 8];
      aq[nt] = __builtin_amdgcn_mfma_f32_16x16x32_bf16(wqf0, bx0, aq[nt], 0, 0, 0);
      aq[nt] = __builtin_amdgcn_mfma_f32_16x16x32_bf16(wqf1, bx1, aq[nt], 0, 0, 0);
    }
#pragma unroll
    for (int nt = 0; nt < 2; ++nt) {
      f16x4 pk;
      pk[0]=(_Float16)aq[nt][0]; pk[1]=(_Float16)aq[nt][1];
      pk[2]=(_Float16)aq[nt][2]; pk[3]=(_Float16)aq[nt][3];
      *(f16x4*)&qcat[thalf * 32 + nt * 16 + lc][mtile * 16 + lr * 4] = pk;
    }
  }
  __syncthreads();

  // stage-1 attention via MFMA; wave w handles head w only.
  {
    _Float16* psw = &pW[w][0][0];
    // hoist ALL group q-frags: rows g*16+lc are never touched by catL writes
    // of other groups -> kills the false qcat WAR that serialized groups.
    f16x8 qf[4];
#pragma unroll
    for (int g = 0; g < 4; ++g) qf[g] = *(const f16x8*)&qcat[g * 16 + lc][w * 8];
#pragma unroll
    for (int g = 0; g < 4; ++g) {
      // S = mfma(agents, q): C col = tok lc, rows = agents at*16+lr*4+j
#pragma unroll
      for (int at = 0; at < 4; ++at) {
        f32x4 sc = __builtin_amdgcn_mfma_f32_16x16x32_f16(
            ba[at], qf[g], (f32x4){0.f, 0.f, 0.f, 0.f}, 0, 0, 0);
        unsigned u0 = pk2(fexp2(sc[0]), fexp2(sc[1]));
        unsigned u1 = pk2(fexp2(sc[2]), fexp2(sc[3]));
        unsigned long long qq = ((unsigned long long)u1 << 32) | u0;
        *(unsigned long long*)&psw[(size_t)lc * 72 + at * 16 + lr * 4] = qq;
      }
      // P B-frags: B[k=agent lr*8+i][n=tok lc] = pW[tok][agent] rows
      f16x8 pA0 = *(const f16x8*)&psw[(size_t)lc * 72 + lr * 8];
      f16x8 pA1 = *(const f16x8*)&psw[(size_t)lc * 72 + 32 + lr * 8];
      // PV swapped: A = pvt[feat][agent], B = P^T -> C col = tok, row = feat
      f32x4 pv = __builtin_amdgcn_mfma_f32_16x16x32_f16(
          pvB0, pA0, (f32x4){0.f, 0.f, 0.f, 0.f}, 0, 0, 0);
      pv = __builtin_amdgcn_mfma_f32_16x16x32_f16(pvB1, pA1, pv, 0, 0, 0);
      // feat row 8 (denominator) lives in lane 32+lc, reg 0
      float den = __shfl(pv[0], 32 + lc);
      float inv = frcp(den);
      if (lr < 2) { // feats lr*4..+3 (0..7 real)
        bf16x4 pc;
        pc[0] = (__bf16)(pv[0] * inv); pc[1] = (__bf16)(pv[1] * inv);
        pc[2] = (__bf16)(pv[2] * inv); pc[3] = (__bf16)(pv[3] * inv);
        *(bf16x4*)((__bf16*)&qcat[g * 16 + lc][0] + w * 8 + lr * 4) = pc;
      }
    }
  }

  // xa-half of out-GEMM + Wo/bias loads: runs in the barrier-wait slack
  // (xa stable since barrier 1; ba/pvB dead -> no VGPR-cap pressure)
  bf16x8 wof0 = ldw8(Wo, w * 16 + lc, lr * 8, 128);
  bf16x8 wof1 = ldw8(Wo, w * 16 + lc, 32 + lr * 8, 128);
  bf16x8 wof2 = ldw8(Wo, w * 16 + lc, 64 + lr * 8, 128);
  bf16x8 wof3 = ldw8(Wo, w * 16 + lc, 96 + lr * 8, 128);
  f32x4 bv = *(const f32x4*)(bo + w * 16 + lr * 4);
  f32x4 acc[4];
#pragma unroll
  for (int i = 0; i < 4; ++i) acc[i] = (f32x4){0.f,0.f,0.f,0.f};
#pragma unroll
  for (int nt = 0; nt < 4; ++nt) {
    bf16x8 b0 = *(const bf16x8*)&xa[nt * 16 + lc][lr * 8];
    bf16x8 b1 = *(const bf16x8*)&xa[nt * 16 + lc][32 + lr * 8];
    acc[nt] = __builtin_amdgcn_mfma_f32_16x16x32_bf16(wof2, b0, acc[nt], 0, 0, 0);
    acc[nt] = __builtin_amdgcn_mfma_f32_16x16x32_bf16(wof3, b1, acc[nt], 0, 0, 0);
  }
  __syncthreads();

  // catL-half + bias + direct stores (short post-barrier tail)
#pragma unroll
  for (int nt = 0; nt < 4; ++nt) {
    bf16x8 c0 = *(const bf16x8*)&qcat[nt * 16 + lc][lr * 8];
    bf16x8 c1 = *(const bf16x8*)&qcat[nt * 16 + lc][32 + lr * 8];
    acc[nt] = __builtin_amdgcn_mfma_f32_16x16x32_bf16(wof0, c0, acc[nt], 0, 0, 0);
    acc[nt] = __builtin_amdgcn_mfma_f32_16x16x32_bf16(wof1, c1, acc[nt], 0, 0, 0);
    f32x4 v = acc[nt] + bv;
    float* dst = out + ((size_t)b * NSEQ + tile * 64 + nt * 16 + lc) * 128 + w * 16 + lr * 4;
    *(f32x4*)dst = v;
  }
}

extern "C" void kernel_launch(void* const* d_in, const int* in_sizes, int n_in,
                              void* d_out, int out_size, void* d_ws, size_t ws_size,
                              hipStream_t stream) {
  (void)in_sizes; (void)n_in; (void)out_size; (void)ws_size;
  const float* x1 = (const float*)d_in[0];
  const float* x2 = (const float*)d_in[1];
  const float* Wq = (const float*)d_in[2];
  const float* Wk = (const float*)d_in[3];
  const float* Wv = (const float*)d_in[4];
  const float* Wo = (const float*)d_in[5];
  const float* bo = (const float*)d_in[6];
  float* out = (float*)d_out;

  us* x1bf = (us*)d_ws;                                   // 32*3136*64 bf16 = 12.85MB
  us* agf16 = x1bf + (size_t)NB * NSEQ * 64;              // 100352 f16
  us* pvp = agf16 + (size_t)NB * NH * NAG * 8;            // 256*24*441 f16 = 5.4MB
  us* pvtF = pvp + (size_t)NB * NH * NPAIR * 441;         // 256*1024 f16
  // total ws ~= 19.3 MB

  agent_x1_kernel<<<dim3(NAG, NB), 256, 0, stream>>>(x1, Wq, x1bf, agf16);
  kv_stage0_kernel<<<dim3(NPAIR, NB), 256, 0, stream>>>(x2, Wk, Wv, agf16, pvp);
  aofin_kernel<<<dim3(NH, NB), 256, 0, stream>>>(pvp, pvtF);
  stage1_out_kernel<<<dim3(NAG, NB), 512, 0, stream>>>(x1bf, Wq, agf16,
                                                       pvtF, Wo, bo, out);
}

// Round 21
// 72.463 us; speedup vs baseline: 1.4946x; 1.0008x over previous
//
#include <hip/hip_runtime.h>
#include <hip/hip_bf16.h>

#define NB 32
#define NSEQ 3136
#define NDIM 64
#define NH 8
#define NAG 49
#define NPAIR 24   // K2: 23 pairs of 2 chunks + 1 triple (46,47,48) = 768 blocks

static constexpr float kScale = 0.35355339059327378f; // 8^-0.5
static constexpr float kLog2e = 1.4426950408889634f;

typedef unsigned short us;
typedef __attribute__((ext_vector_type(8))) __bf16 bf16x8;
typedef __attribute__((ext_vector_type(4))) __bf16 bf16x4;
typedef __attribute__((ext_vector_type(2))) _Float16 f16x2;
typedef __attribute__((ext_vector_type(4))) _Float16 f16x4;
typedef __attribute__((ext_vector_type(8))) _Float16 f16x8;
typedef __attribute__((ext_vector_type(4))) float f32x4;

__device__ __forceinline__ float fexp2(float x) {
#if __has_builtin(__builtin_amdgcn_exp2f)
  return __builtin_amdgcn_exp2f(x);
#else
  return exp2f(x);
#endif
}

__device__ __forceinline__ float frcp(float x) {
#if __has_builtin(__builtin_amdgcn_rcpf)
  return __builtin_amdgcn_rcpf(x);
#else
  return 1.f / x;
#endif
}

__device__ __forceinline__ unsigned pk2(float a, float b) { // pack 2 f32 -> f16x2
#if __has_builtin(__builtin_amdgcn_cvt_pkrtz)
  return __builtin_bit_cast(unsigned, __builtin_amdgcn_cvt_pkrtz(a, b));
#else
  f16x2 v = {(_Float16)a, (_Float16)b};
  return __builtin_bit_cast(unsigned, v);
#endif
}

__device__ __forceinline__ bf16x8 ldw8(const float* W, int row, int c0, int ld) {
  const float4* p = (const float4*)(W + (size_t)row * ld + c0);
  float4 v0 = p[0], v1 = p[1];
  bf16x8 r;
  r[0]=(__bf16)v0.x; r[1]=(__bf16)v0.y; r[2]=(__bf16)v0.z; r[3]=(__bf16)v0.w;
  r[4]=(__bf16)v1.x; r[5]=(__bf16)v1.y; r[6]=(__bf16)v1.z; r[7]=(__bf16)v1.w;
  return r;
}

// ---------------------------------------------------------------------------
// K1: agent table + x1 -> bf16 (staged in stage1's fragment layout).
//   agf16[b,h,a][8] = log2e*kScale*(chunkmean(x1)) @ Wq^T   (f32 math)
//   x1bf[(b*49+a)*8 + h][tok 64][8]  bf16  (16B/lane coalesced for stage1)
// grid (49, 32), block 256.
// ---------------------------------------------------------------------------
__global__ __launch_bounds__(256) void agent_x1_kernel(
    const float* __restrict__ x1, const float* __restrict__ Wq,
    us* __restrict__ x1bf, us* __restrict__ agf16) {
  __shared__ float red[4][64];
  __shared__ float marr[64];
  const int a = blockIdx.x, b = blockIdx.y, t = threadIdx.x;
  const int i64 = t & 63, cb = t >> 6;

  // row-read: row i64, cols cb*16..+15 -> bf16 -> x1bf (two 8-col groups)
  {
    const float4* s1 = (const float4*)(x1 + ((size_t)(b * NSEQ) + a * 64 + i64) * NDIM + cb * 16);
    float4 v0 = s1[0], v1 = s1[1], v2 = s1[2], v3 = s1[3];
    bf16x8 p0, p1;
    p0[0]=(__bf16)v0.x; p0[1]=(__bf16)v0.y; p0[2]=(__bf16)v0.z; p0[3]=(__bf16)v0.w;
    p0[4]=(__bf16)v1.x; p0[5]=(__bf16)v1.y; p0[6]=(__bf16)v1.z; p0[7]=(__bf16)v1.w;
    p1[0]=(__bf16)v2.x; p1[1]=(__bf16)v2.y; p1[2]=(__bf16)v2.z; p1[3]=(__bf16)v2.w;
    p1[4]=(__bf16)v3.x; p1[5]=(__bf16)v3.y; p1[6]=(__bf16)v3.z; p1[7]=(__bf16)v3.w;
    __bf16* dst = (__bf16*)x1bf;
    *(bf16x8*)(dst + ((((size_t)b * NAG + a) * 8 + cb * 2) * 64 + i64) * 8) = p0;
    *(bf16x8*)(dst + ((((size_t)b * NAG + a) * 8 + cb * 2 + 1) * 64 + i64) * 8) = p1;
  }
  // x1 column partial sums (coalesced; L1/L2 hit after the row-read)
  {
    const float* xc = x1 + ((size_t)(b * NSEQ) + a * 64 + cb * 16) * NDIM + i64;
    float cs = 0.f;
#pragma unroll
    for (int i = 0; i < 16; ++i) cs += xc[i * NDIM];
    red[cb][i64] = cs;
  }
  __syncthreads();
  if (t < 64) marr[t] = red[0][t] + red[1][t] + red[2][t] + red[3][t];
  __syncthreads();
  if (t < 64) {
    const float4* wqr = (const float4*)(Wq + (size_t)t * NDIM);
    const float4* mm = (const float4*)marr;
    float s0 = 0.f;
#pragma unroll
    for (int i = 0; i < 16; ++i) {
      float4 wv4 = wqr[i], m4 = mm[i];
      s0 += wv4.x * m4.x + wv4.y * m4.y + wv4.z * m4.z + wv4.w * m4.w;
    }
    const float val = s0 * (kScale * kLog2e / 64.f);
    ((_Float16*)agf16)[(((size_t)b * NH + (t >> 3)) * NAG + a) * 8 + (t & 7)] =
        (_Float16)val;
  }
}

// ---------------------------------------------------------------------------
// K2: fused kv-GEMM + stage-0 attention; 2 chunks/block (last pair: 3) with
// in-register PV accumulation across chunks. grid (24, 32) = 768 blocks =
// EXACTLY 3 blocks/CU x 256 CUs -> single dispatch round, no tail.
// Partials stored ONCE as f16 to pvp[bh][pair 24][441]. No atomics/fences.
// ---------------------------------------------------------------------------
__global__ __launch_bounds__(256) void kv_stage0_kernel(
    const float* __restrict__ x2, const float* __restrict__ Wk,
    const float* __restrict__ Wv, const us* __restrict__ agf16,
    us* __restrict__ pvp) {
  __shared__ __align__(16) __bf16 xb[64][72];        // 9216
  __shared__ __align__(16) _Float16 klds[4][64][24]; // 12288 [wave][tok][feat16+pad]
  __shared__ __align__(16) _Float16 vlds[4][18][72]; // 10368 [wave][feat16|ones][tok]
  __shared__ __align__(16) _Float16 plds[4][64][40]; // 20480 [wave][agent][tok32+pad]
  const int pair = blockIdx.x, b = blockIdx.y, t = threadIdx.x;
  const int i64 = t & 63, cb = t >> 6;
  const int w = cb, lr = (t >> 4) & 3, lc = t & 15;
  const int nch = (pair == NPAIR - 1) ? 3 : 2;

  // weight A-frags inline-converted from f32 (L2-resident after first blocks)
  bf16x8 ak0 = ldw8(Wk, w * 16 + lc, lr * 8, NDIM);
  bf16x8 ak1 = ldw8(Wk, w * 16 + lc, 32 + lr * 8, NDIM);
  bf16x8 av0 = ldw8(Wv, w * 16 + lc, lr * 8, NDIM);
  bf16x8 av1 = ldw8(Wv, w * 16 + lc, 32 + lr * 8, NDIM);

  // agent B-frags for this wave's two heads (zero for k>=8: pad-kill); once
  const size_t bh0 = (size_t)b * NH + 2 * w;
  f16x8 ba[2][4];
#pragma unroll
  for (int hh = 0; hh < 2; ++hh)
#pragma unroll
    for (int at = 0; at < 4; ++at) {
      f16x8 v = (f16x8)(_Float16)0.0f;
      if (lr == 0) {
        int row = at * 16 + lc; if (row > 48) row = 48;
        v = *(const f16x8*)(agf16 + (bh0 + hh) * (NAG * 8) + row * 8);
      }
      ba[hh][at] = v;
    }
  vlds[w][16][i64] = (_Float16)1.0f; // ones row -> denominator column (persists)

  f32x4 accPV[2][4];
#pragma unroll
  for (int hh = 0; hh < 2; ++hh)
#pragma unroll
    for (int i = 0; i < 4; ++i) accPV[hh][i] = (f32x4){0.f, 0.f, 0.f, 0.f};

  for (int cc = 0; cc < nch; ++cc) {
    const int a = pair * 2 + cc; // last pair: 46,47,48
    if (cc) __syncthreads(); // all waves done reading xb of prev chunk

    // stage x2 tile as bf16 (thread: one row, 16 cols)
    {
      const float4* s2 = (const float4*)(x2 + ((size_t)(b * NSEQ) + a * 64 + i64) * NDIM + cb * 16);
      float4 v0 = s2[0], v1 = s2[1], v2 = s2[2], v3 = s2[3];
      bf16x8 p0, p1;
      p0[0]=(__bf16)v0.x; p0[1]=(__bf16)v0.y; p0[2]=(__bf16)v0.z; p0[3]=(__bf16)v0.w;
      p0[4]=(__bf16)v1.x; p0[5]=(__bf16)v1.y; p0[6]=(__bf16)v1.z; p0[7]=(__bf16)v1.w;
      p1[0]=(__bf16)v2.x; p1[1]=(__bf16)v2.y; p1[2]=(__bf16)v2.z; p1[3]=(__bf16)v2.w;
      p1[4]=(__bf16)v3.x; p1[5]=(__bf16)v3.y; p1[6]=(__bf16)v3.z; p1[7]=(__bf16)v3.w;
      *(bf16x8*)&xb[i64][cb * 16] = p0; *(bf16x8*)&xb[i64][cb * 16 + 8] = p1;
    }
    __syncthreads();

    // kv^T GEMM: wave w = feats w*16..+15
    f32x4 acck[4], accv[4];
#pragma unroll
    for (int i = 0; i < 4; ++i) {
      acck[i] = (f32x4){0.f, 0.f, 0.f, 0.f};
      accv[i] = (f32x4){0.f, 0.f, 0.f, 0.f};
    }
#pragma unroll
    for (int nt = 0; nt < 4; ++nt) {
      bf16x8 x0 = *(const bf16x8*)&xb[nt * 16 + lc][lr * 8];
      bf16x8 x1f = *(const bf16x8*)&xb[nt * 16 + lc][32 + lr * 8];
      acck[nt] = __builtin_amdgcn_mfma_f32_16x16x32_bf16(ak0, x0, acck[nt], 0, 0, 0);
      acck[nt] = __builtin_amdgcn_mfma_f32_16x16x32_bf16(ak1, x1f, acck[nt], 0, 0, 0);
      accv[nt] = __builtin_amdgcn_mfma_f32_16x16x32_bf16(av0, x0, accv[nt], 0, 0, 0);
      accv[nt] = __builtin_amdgcn_mfma_f32_16x16x32_bf16(av1, x1f, accv[nt], 0, 0, 0);
    }
    // wave-private relayout (no barriers; same-wave produce->consume).
#pragma unroll
    for (int nt = 0; nt < 4; ++nt) {
      f16x4 pk4;
      pk4[0]=(_Float16)acck[nt][0]; pk4[1]=(_Float16)acck[nt][1];
      pk4[2]=(_Float16)acck[nt][2]; pk4[3]=(_Float16)acck[nt][3];
      *(f16x4*)&klds[w][nt * 16 + lc][lr * 4] = pk4;
#pragma unroll
      for (int j = 0; j < 4; ++j)
        vlds[w][lr * 4 + j][nt * 16 + lc] = (_Float16)accv[nt][j];
    }

#pragma unroll
    for (int hh = 0; hh < 2; ++hh) {
#pragma unroll
      for (int half = 0; half < 2; ++half) {
        // S for 32 tokens: A = k[tok][feat(8 real)], B = agents
#pragma unroll
        for (int tb = 0; tb < 2; ++tb) {
          const int tokbase = half * 32 + tb * 16;
          f16x8 kf = *(const f16x8*)&klds[w][tokbase + lc][hh * 8];
#pragma unroll
          for (int at = 0; at < 4; ++at) {
            f32x4 sc = __builtin_amdgcn_mfma_f32_16x16x32_f16(
                kf, ba[hh][at], (f32x4){0.f, 0.f, 0.f, 0.f}, 0, 0, 0);
            // C: row = tok tb*16+lr*4+j (in-half), col = agent at*16+lc
            unsigned u0 = pk2(fexp2(sc[0]), fexp2(sc[1]));
            unsigned u1 = pk2(fexp2(sc[2]), fexp2(sc[3]));
            unsigned long long q = ((unsigned long long)u1 << 32) | u0;
            *(unsigned long long*)&plds[w][at * 16 + lc][tb * 16 + lr * 4] = q;
          }
        }
        // PV over these 32 tokens: A = P[agent][tok], B = V'[tok][feat|ones]
        const int frow = (lc < 8) ? hh * 8 + lc : 16;
        f16x8 vf = *(const f16x8*)&vlds[w][frow][half * 32 + lr * 8];
#pragma unroll
        for (int at = 0; at < 4; ++at) {
          f16x8 pf = *(const f16x8*)&plds[w][at * 16 + lc][lr * 8];
          accPV[hh][at] =
              __builtin_amdgcn_mfma_f32_16x16x32_f16(pf, vf, accPV[hh][at], 0, 0, 0);
        }
      }
    }
  }

  // store pair-partials ONCE (f16): C row = agent at*16+lr*4+j, col = feat lc
#pragma unroll
  for (int hh = 0; hh < 2; ++hh) {
    if (lc < 9) {
      _Float16* dst = (_Float16*)pvp + ((bh0 + hh) * NPAIR + pair) * 441;
#pragma unroll
      for (int at = 0; at < 4; ++at)
#pragma unroll
        for (int j = 0; j < 4; ++j) {
          const int ag = at * 16 + lr * 4 + j;
          if (ag < NAG) dst[ag * 9 + lc] = (_Float16)accPV[hh][at][j];
        }
    }
  }
}

// ---------------------------------------------------------------------------
// K3: sum 24 pair-partials (contiguous f16 21KB per bh), normalize, emit
// transposed PV table pvtF[b,h][feat 16][agent 64] f16 (feat 8 = ones).
// grid (NH, NB), block 256.
// ---------------------------------------------------------------------------
__global__ __launch_bounds__(256) void aofin_kernel(
    const us* __restrict__ pvp, us* __restrict__ pvtF) {
  __shared__ float acc[441];
  const int h = blockIdx.x, b = blockIdx.y, t = threadIdx.x;
  const size_t bh = (size_t)b * NH + h;
  const _Float16* src = (const _Float16*)pvp + bh * (NPAIR * 441);
  for (int s = t; s < 441; s += 256) {
    float v = 0.f;
#pragma unroll 6
    for (int p = 0; p < NPAIR; ++p) v += (float)src[(size_t)p * 441 + s];
    acc[s] = v;
  }
  __syncthreads();
  if (t < 64) {
    us* col = pvtF + bh * 1024 + t;
    float inv = (t < NAG) ? frcp(acc[t * 9 + 8]) : 0.f;
#pragma unroll
    for (int f = 0; f < 8; ++f) {
      float val = (t < NAG) ? acc[t * 9 + f] * inv : 0.f;
      _Float16 hv = (_Float16)val;
      col[f * 64] = __builtin_bit_cast(us, hv);
    }
    col[8 * 64] = (t < NAG) ? (us)0x3C00 : (us)0;
#pragma unroll
    for (int f = 9; f < 16; ++f) col[f * 64] = 0;
  }
}

// ---------------------------------------------------------------------------
// K4: stage-1 attention (MFMA) + output linear, fused. pW stride 72 f16
// (bank-minimal). PV operands swapped (lane = 4 consecutive feats of 1 token).
// qf fragments hoisted; epilogue re-pipelined (xa-half + Wo/bias pre-barrier).
// BYTE-IDENTICAL to the verified r15/r17/r19/r20 kernel.
// grid (49, 32), block 512 (8 waves; wave w = head w).
// ---------------------------------------------------------------------------
__global__ __launch_bounds__(512, 8) void stage1_out_kernel(
    const us* __restrict__ x1bf, const float* __restrict__ Wq,
    const us* __restrict__ agf16, const us* __restrict__ pvtF,
    const float* __restrict__ Wo, const float* __restrict__ bo,
    float* __restrict__ out) {
  __shared__ __align__(16) __bf16 xa[64][72];      // 9216
  __shared__ __align__(16) us qcat[64][72];        // 9216 (q f16, then catL bf16)
  __shared__ __align__(16) _Float16 pW[8][16][72]; // 18432 per-wave P tiles
  const int tile = blockIdx.x, b = blockIdx.y;
  const int t = threadIdx.x, tokl = t & 63, h = t >> 6;
  const int w = h, lane = t & 63, lr = (lane >> 4) & 3, lc = lane & 15;
  const int mtile = w & 3, thalf = w >> 2;
  const size_t bh = (size_t)b * NH + w;

  // q-weight frags inline from f32
  bf16x8 wqf0 = ldw8(Wq, mtile * 16 + lc, lr * 8, NDIM);
  bf16x8 wqf1 = ldw8(Wq, mtile * 16 + lc, 32 + lr * 8, NDIM);

  // agent-table MFMA frags (ONCE per wave)
  f16x8 ba[4];
#pragma unroll
  for (int at = 0; at < 4; ++at) {
    f16x8 v = (f16x8)(_Float16)0.0f;
    if (lr == 0) {
      int row = at * 16 + lc; if (row > 48) row = 48;
      v = *(const f16x8*)(agf16 + bh * (NAG * 8) + row * 8);
    }
    ba[at] = v;
  }
  // pvt frags: A[m=feat lc][k=agent lr*8+i] (agents 32.. in pvB1)
  const us* pvb = pvtF + bh * 1024;
  f16x8 pvB0 = *(const f16x8*)(pvb + lc * 64 + lr * 8);
  f16x8 pvB1 = *(const f16x8*)(pvb + lc * 64 + 32 + lr * 8);

  // stage x1 tile from x1bf (16B/lane, fully coalesced)
  {
    bf16x8 p = *(const bf16x8*)((const __bf16*)x1bf +
        ((((size_t)b * NAG + tile) * 8 + h) * 64 + tokl) * 8);
    *(bf16x8*)&xa[tokl][h * 8] = p;
  }
  __syncthreads();

  // q^T = Wq @ x1^T -> qcat as f16
  {
    f32x4 aq[2];
    aq[0] = (f32x4){0.f,0.f,0.f,0.f}; aq[1] = (f32x4){0.f,0.f,0.f,0.f};
#pragma unroll
    for (int nt = 0; nt < 2; ++nt) {
      bf16x8 bx0 = *(const bf16x8*)&xa[thalf * 32 + nt * 16 + lc][lr * 8];
      bf16x8 bx1 = *(const bf16x8*)&xa[thalf * 32 + nt * 16 + lc][32 + lr * 8];
      aq[nt] = __builtin_amdgcn_mfma_f32_16x16x32_bf16(wqf0, bx0, aq[nt], 0, 0, 0);
      aq[nt] = __builtin_amdgcn_mfma_f32_16x16x32_bf16(wqf1, bx1, aq[nt], 0, 0, 0);
    }
#pragma unroll
    for (int nt = 0; nt < 2; ++nt) {
      f16x4 pk;
      pk[0]=(_Float16)aq[nt][0]; pk[1]=(_Float16)aq[nt][1];
      pk[2]=(_Float16)aq[nt][2]; pk[3]=(_Float16)aq[nt][3];
      *(f16x4*)&qcat[thalf * 32 + nt * 16 + lc][mtile * 16 + lr * 4] = pk;
    }
  }
  __syncthreads();

  // stage-1 attention via MFMA; wave w handles head w only.
  {
    _Float16* psw = &pW[w][0][0];
    // hoist ALL group q-frags: rows g*16+lc are never touched by catL writes
    // of other groups -> kills the false qcat WAR that serialized groups.
    f16x8 qf[4];
#pragma unroll
    for (int g = 0; g < 4; ++g) qf[g] = *(const f16x8*)&qcat[g * 16 + lc][w * 8];
#pragma unroll
    for (int g = 0; g < 4; ++g) {
      // S = mfma(agents, q): C col = tok lc, rows = agents at*16+lr*4+j
#pragma unroll
      for (int at = 0; at < 4; ++at) {
        f32x4 sc = __builtin_amdgcn_mfma_f32_16x16x32_f16(
            ba[at], qf[g], (f32x4){0.f, 0.f, 0.f, 0.f}, 0, 0, 0);
        unsigned u0 = pk2(fexp2(sc[0]), fexp2(sc[1]));
        unsigned u1 = pk2(fexp2(sc[2]), fexp2(sc[3]));
        unsigned long long qq = ((unsigned long long)u1 << 32) | u0;
        *(unsigned long long*)&psw[(size_t)lc * 72 + at * 16 + lr * 4] = qq;
      }
      // P B-frags: B[k=agent lr*8+i][n=tok lc] = pW[tok][agent] rows
      f16x8 pA0 = *(const f16x8*)&psw[(size_t)lc * 72 + lr * 8];
      f16x8 pA1 = *(const f16x8*)&psw[(size_t)lc * 72 + 32 + lr * 8];
      // PV swapped: A = pvt[feat][agent], B = P^T -> C col = tok, row = feat
      f32x4 pv = __builtin_amdgcn_mfma_f32_16x16x32_f16(
          pvB0, pA0, (f32x4){0.f, 0.f, 0.f, 0.f}, 0, 0, 0);
      pv = __builtin_amdgcn_mfma_f32_16x16x32_f16(pvB1, pA1, pv, 0, 0, 0);
      // feat row 8 (denominator) lives in lane 32+lc, reg 0
      float den = __shfl(pv[0], 32 + lc);
      float inv = frcp(den);
      if (lr < 2) { // feats lr*4..+3 (0..7 real)
        bf16x4 pc;
        pc[0] = (__bf16)(pv[0] * inv); pc[1] = (__bf16)(pv[1] * inv);
        pc[2] = (__bf16)(pv[2] * inv); pc[3] = (__bf16)(pv[3] * inv);
        *(bf16x4*)((__bf16*)&qcat[g * 16 + lc][0] + w * 8 + lr * 4) = pc;
      }
    }
  }

  // xa-half of out-GEMM + Wo/bias loads: runs in the barrier-wait slack
  // (xa stable since barrier 1; ba/pvB dead -> no VGPR-cap pressure)
  bf16x8 wof0 = ldw8(Wo, w * 16 + lc, lr * 8, 128);
  bf16x8 wof1 = ldw8(Wo, w * 16 + lc, 32 + lr * 8, 128);
  bf16x8 wof2 = ldw8(Wo, w * 16 + lc, 64 + lr * 8, 128);
  bf16x8 wof3 = ldw8(Wo, w * 16 + lc, 96 + lr * 8, 128);
  f32x4 bv = *(const f32x4*)(bo + w * 16 + lr * 4);
  f32x4 acc[4];
#pragma unroll
  for (int i = 0; i < 4; ++i) acc[i] = (f32x4){0.f,0.f,0.f,0.f};
#pragma unroll
  for (int nt = 0; nt < 4; ++nt) {
    bf16x8 b0 = *(const bf16x8*)&xa[nt * 16 + lc][lr * 8];
    bf16x8 b1 = *(const bf16x8*)&xa[nt * 16 + lc][32 + lr * 8];
    acc[nt] = __builtin_amdgcn_mfma_f32_16x16x32_bf16(wof2, b0, acc[nt], 0, 0, 0);
    acc[nt] = __builtin_amdgcn_mfma_f32_16x16x32_bf16(wof3, b1, acc[nt], 0, 0, 0);
  }
  __syncthreads();

  // catL-half + bias + direct stores (short post-barrier tail)
#pragma unroll
  for (int nt = 0; nt < 4; ++nt) {
    bf16x8 c0 = *(const bf16x8*)&qcat[nt * 16 + lc][lr * 8];
    bf16x8 c1 = *(const bf16x8*)&qcat[nt * 16 + lc][32 + lr * 8];
    acc[nt] = __builtin_amdgcn_mfma_f32_16x16x32_bf16(wof0, c0, acc[nt], 0, 0, 0);
    acc[nt] = __builtin_amdgcn_mfma_f32_16x16x32_bf16(wof1, c1, acc[nt], 0, 0, 0);
    f32x4 v = acc[nt] + bv;
    float* dst = out + ((size_t)b * NSEQ + tile * 64 + nt * 16 + lc) * 128 + w * 16 + lr * 4;
    *(f32x4*)dst = v;
  }
}

extern "C" void kernel_launch(void* const* d_in, const int* in_sizes, int n_in,
                              void* d_out, int out_size, void* d_ws, size_t ws_size,
                              hipStream_t stream) {
  (void)in_sizes; (void)n_in; (void)out_size; (void)ws_size;
  const float* x1 = (const float*)d_in[0];
  const float* x2 = (const float*)d_in[1];
  const float* Wq = (const float*)d_in[2];
  const float* Wk = (const float*)d_in[3];
  const float* Wv = (const float*)d_in[4];
  const float* Wo = (const float*)d_in[5];
  const float* bo = (const float*)d_in[6];
  float* out = (float*)d_out;

  us* x1bf = (us*)d_ws;                                   // 32*3136*64 bf16 = 12.85MB
  us* agf16 = x1bf + (size_t)NB * NSEQ * 64;              // 100352 f16
  us* pvp = agf16 + (size_t)NB * NH * NAG * 8;            // 256*24*441 f16 = 5.4MB
  us* pvtF = pvp + (size_t)NB * NH * NPAIR * 441;         // 256*1024 f16
  // total ws ~= 19.3 MB

  agent_x1_kernel<<<dim3(NAG, NB), 256, 0, stream>>>(x1, Wq, x1bf, agf16);
  kv_stage0_kernel<<<dim3(NPAIR, NB), 256, 0, stream>>>(x2, Wk, Wv, agf16, pvp);
  aofin_kernel<<<dim3(NH, NB), 256, 0, stream>>>(pvp, pvtF);
  stage1_out_kernel<<<dim3(NAG, NB), 512, 0, stream>>>(x1bf, Wq, agf16,
                                                       pvtF, Wo, bo, out);
}